// Round 1
// baseline (198.469 us; speedup 1.0000x reference)
//
#include <hip/hip_runtime.h>

// ManifoldCrossAttention on MI355X (gfx950), bf16 MFMA pipeline, f32 I/O.
//
// Pipeline (5 kernels, all on `stream`):
//  1. k_cvt_w   : Wq/Wk/Wv/Wo f32 -> bf16 (row-major = K-contiguous for A-frags)
//  2. k_pack_xt : feats [b][c][n] f32 -> Xt [b][m=f*576+n][c] bf16 (K-contig B operand)
//  3. k_gemm_qkv: Q=WqX, K=WkX, V=WvX.  Q,K stored transposed [m][c]; V natural [c][m]
//  4. k_attn    : per (b,h,f,n-tile32): S=Q^T K (mfma), p=exp(s/8) (no-max softmax,
//                 scores are tiny), PV via mfma with P transposed through per-wave LDS,
//                 waves split KV 4-way, combined + normalized in epilogue -> Ot [m][c]
//  5. k_gemm_out: out = Wo @ O + bo + feat (residual), f32 stores to d_out
//
// Workspace layout (bytes):           size
//   Wb  @ 0         4*512*512*2   = 2097152
//   Xt  @ 2097152   4*1728*512*2  = 7077888   (aliased by Ot after attn)
//   Qt  @ 9175040   7077888
//   Kt  @ 16252928  7077888
//   Vn  @ 23330816  7077888       total 30408704 B

using bf16x8 = __attribute__((ext_vector_type(8))) short;           // 8 bf16 = 4 VGPR
using f32x4  = __attribute__((ext_vector_type(4))) float;
using u16x4  = __attribute__((ext_vector_type(4))) unsigned short;
using u16x8  = __attribute__((ext_vector_type(8))) unsigned short;

#define MFMA16(a, b, c) __builtin_amdgcn_mfma_f32_16x16x32_bf16((a), (b), (c), 0, 0, 0)

__device__ __forceinline__ unsigned short f2bf(float f) {
  unsigned int u = __float_as_uint(f);
  return (unsigned short)((u + 0x7fffu + ((u >> 16) & 1u)) >> 16);  // RNE
}

// ---------------------------------------------------------------- weights cvt
__global__ __launch_bounds__(256) void k_cvt_w(
    const float* __restrict__ Wq, const float* __restrict__ Wk,
    const float* __restrict__ Wv, const float* __restrict__ Wo,
    unsigned short* __restrict__ Wb) {
  int i   = blockIdx.x * 256 + threadIdx.x;  // 1024 blocks * 256 thr * 4 elem = 4*512*512
  int idx = i * 4;
  int sel = idx >> 18;                       // 262144 elems per matrix
  const float* s = sel == 0 ? Wq : sel == 1 ? Wk : sel == 2 ? Wv : Wo;
  f32x4 v = *(const f32x4*)(s + (idx & 262143));
  u16x4 o;
  o[0] = f2bf(v[0]); o[1] = f2bf(v[1]); o[2] = f2bf(v[2]); o[3] = f2bf(v[3]);
  *(u16x4*)(Wb + idx) = o;
}

// ------------------------------------------------------- pack X^T (transpose)
__global__ __launch_bounds__(256) void k_pack_xt(
    const float* __restrict__ f0, const float* __restrict__ f1,
    const float* __restrict__ f2, unsigned short* __restrict__ Xt) {
  const int nt = blockIdx.x;            // 0..8  (n tile of 64)
  const int ct = blockIdx.y;            // 0..7  (c tile of 64)
  const int z  = blockIdx.z;            // b*3+f
  const int b = z / 3, f = z % 3;
  const int t = threadIdx.x;
  const float* src = (f == 0 ? f0 : f == 1 ? f1 : f2) + b * (512 * 576);

  __shared__ unsigned short tile[64][65];  // +1 pad breaks bank conflicts on read
#pragma unroll
  for (int i = 0; i < 16; ++i) {
    int idx = i * 256 + t;
    int cc = idx >> 6, nn = idx & 63;    // coalesced over nn
    tile[cc][nn] = f2bf(src[(ct * 64 + cc) * 576 + nt * 64 + nn]);
  }
  __syncthreads();
  const int row0 = b * 1728 + f * 576 + nt * 64;
#pragma unroll
  for (int i = 0; i < 16; ++i) {
    int idx = i * 256 + t;
    int nn = idx >> 6, cc = idx & 63;    // coalesced over cc
    Xt[(row0 + nn) * 512 + ct * 64 + cc] = tile[cc][nn];
  }
}

// ---------------------------------------------------------------- QKV GEMM
// C[o][m] = sum_c W[o][c] * Xt[m][c]  (+bias).  Per-wave 64x64 tile, 4x4 frags,
// fragments loaded directly from global (all K-contiguous, 16B per lane).
__global__ __launch_bounds__(256) void k_gemm_qkv(
    const unsigned short* __restrict__ Wb, const unsigned short* __restrict__ Xt,
    const float* __restrict__ bq, const float* __restrict__ bk,
    const float* __restrict__ bv,
    unsigned short* __restrict__ Qt, unsigned short* __restrict__ Kt,
    unsigned short* __restrict__ Vn) {
  const int z = blockIdx.z, b = z / 3, p = z % 3;
  const int t = threadIdx.x, w = t >> 6, l = t & 63, lg = l >> 4, lr = l & 15;
  const int wid = blockIdx.x * 4 + w;          // 0..215 = 8 mtiles * 27 ntiles
  const int mt = wid / 27, ntw = wid % 27;
  const int o0 = mt * 64;
  const unsigned short* A = Wb + p * (512 * 512);
  const unsigned short* B = Xt + (b * 1728 + ntw * 64) * 512;

  f32x4 acc[4][4];
#pragma unroll
  for (int fr = 0; fr < 4; ++fr)
#pragma unroll
    for (int fc = 0; fc < 4; ++fc) acc[fr][fc] = (f32x4){0.f, 0.f, 0.f, 0.f};

#pragma unroll 2
  for (int ks = 0; ks < 16; ++ks) {
    const int k0 = ks * 32;
    bf16x8 af[4], bfv[4];
#pragma unroll
    for (int fr = 0; fr < 4; ++fr)
      af[fr] = *(const bf16x8*)(A + (o0 + fr * 16 + lr) * 512 + k0 + lg * 8);
#pragma unroll
    for (int fc = 0; fc < 4; ++fc)
      bfv[fc] = *(const bf16x8*)(B + (fc * 16 + lr) * 512 + k0 + lg * 8);
#pragma unroll
    for (int fr = 0; fr < 4; ++fr)
#pragma unroll
      for (int fc = 0; fc < 4; ++fc)
        acc[fr][fc] = MFMA16(af[fr], bfv[fc], acc[fr][fc]);
  }

  const float* bias = p == 0 ? bq : p == 1 ? bk : bv;
#pragma unroll
  for (int fr = 0; fr < 4; ++fr) {
    f32x4 b4 = *(const f32x4*)(bias + o0 + fr * 16 + lg * 4);
#pragma unroll
    for (int fc = 0; fc < 4; ++fc) {
      if (p < 2) {  // Q,K stored transposed: [b*1728+m][o]
        unsigned short* outT = (p == 0) ? Qt : Kt;
        int mrow = b * 1728 + ntw * 64 + fc * 16 + lr;
        u16x4 pk;
#pragma unroll
        for (int r = 0; r < 4; ++r) pk[r] = f2bf(acc[fr][fc][r] + b4[r]);
        *(u16x4*)(outT + mrow * 512 + o0 + fr * 16 + lg * 4) = pk;
      } else {      // V natural: [b*512+o][m]
        int mcol = ntw * 64 + fc * 16 + lr;
#pragma unroll
        for (int r = 0; r < 4; ++r) {
          int o = o0 + fr * 16 + lg * 4 + r;
          Vn[(b * 512 + o) * 1728 + mcol] = f2bf(acc[fr][fc][r] + b4[r]);
        }
      }
    }
  }
}

// ---------------------------------------------------------------- attention
// Per block: (b, h, f, 32 q-rows). 4 waves split the 54 KV-steps (32 each).
// No-max online softmax: p = exp(s/8); unnormalized O + row-sum l accumulated,
// combined across waves and normalized in the epilogue.
__global__ __launch_bounds__(256) void k_attn(
    const unsigned short* __restrict__ Qt, const unsigned short* __restrict__ Kt,
    const unsigned short* __restrict__ V, unsigned short* __restrict__ Ot) {
  const int nt = blockIdx.x;                 // 0..17
  const int hf = blockIdx.y;                 // h*3+f
  const int b  = blockIdx.z;
  const int h = hf / 3, f = hf % 3;
  const int t = threadIdx.x, w = t >> 6, l = t & 63, lg = l >> 4, lr = l & 15;
  const int n0 = nt * 32;
  const int qrow0 = b * 1728 + f * 576 + n0;

  __shared__ __align__(16) unsigned char Pl[4][2560];  // per-wave P [32 n][80B row]
  __shared__ float Obuf[4][64][33];
  __shared__ float Lbuf[4][32];

  // Q fragments (hoisted; rows = n, k = d)
  bf16x8 aq[2][2];
#pragma unroll
  for (int fn = 0; fn < 2; ++fn)
#pragma unroll
    for (int ks = 0; ks < 2; ++ks)
      aq[fn][ks] = *(const bf16x8*)(Qt + (qrow0 + fn * 16 + lr) * 512 + h * 64 +
                                    ks * 32 + lg * 8);

  f32x4 oacc[2][4];
  float lsum[2][4];
#pragma unroll
  for (int fn = 0; fn < 2; ++fn) {
#pragma unroll
    for (int df = 0; df < 4; ++df) oacc[fn][df] = (f32x4){0.f, 0.f, 0.f, 0.f};
#pragma unroll
    for (int r = 0; r < 4; ++r) lsum[fn][r] = 0.f;
  }

  const unsigned short* Ktb = Kt + (b * 1728) * 512 + h * 64;
  const unsigned short* Vb  = V + (b * 512 + h * 64) * 1728;

  for (int sm = w; sm < 54; sm += 4) {   // this wave's KV steps (32 wide)
    const int m0 = sm * 32;
    // ---- S = Q^T K  (rows n, cols m)
    bf16x8 bkf[2][2];
#pragma unroll
    for (int ms = 0; ms < 2; ++ms)
#pragma unroll
      for (int ks = 0; ks < 2; ++ks)
        bkf[ms][ks] = *(const bf16x8*)(Ktb + (m0 + ms * 16 + lr) * 512 +
                                       ks * 32 + lg * 8);
    f32x4 sfr[2][2];
#pragma unroll
    for (int fn = 0; fn < 2; ++fn)
#pragma unroll
      for (int ms = 0; ms < 2; ++ms) {
        f32x4 a = (f32x4){0.f, 0.f, 0.f, 0.f};
        a = MFMA16(aq[fn][0], bkf[ms][0], a);
        a = MFMA16(aq[fn][1], bkf[ms][1], a);
        sfr[fn][ms] = a;
      }
    // ---- softmax partial + P scatter into per-wave LDS [n][m] (bf16)
#pragma unroll
    for (int fn = 0; fn < 2; ++fn)
#pragma unroll
      for (int ms = 0; ms < 2; ++ms)
#pragma unroll
        for (int r = 0; r < 4; ++r) {
          float p = __expf(sfr[fn][ms][r] * 0.125f);
          lsum[fn][r] += p;
          *(unsigned short*)(&Pl[w][(fn * 16 + lg * 4 + r) * 80 +
                                    (ms * 16 + lr) * 2]) = f2bf(p);
        }
    asm volatile("s_waitcnt lgkmcnt(0)" ::: "memory");
    // ---- PV:  O[d][n] += V[d][m] * P[n][m]
    bf16x8 bp0 = *(const bf16x8*)(&Pl[w][(0 * 16 + lr) * 80 + lg * 16]);
    bf16x8 bp1 = *(const bf16x8*)(&Pl[w][(1 * 16 + lr) * 80 + lg * 16]);
#pragma unroll
    for (int df = 0; df < 4; ++df) {
      bf16x8 av = *(const bf16x8*)(Vb + (df * 16 + lr) * 1728 + m0 + lg * 8);
      oacc[0][df] = MFMA16(av, bp0, oacc[0][df]);
      oacc[1][df] = MFMA16(av, bp1, oacc[1][df]);
    }
  }

  // ---- reduce row-sums across the 16 columns (lanes sharing lg)
#pragma unroll
  for (int fn = 0; fn < 2; ++fn)
#pragma unroll
    for (int r = 0; r < 4; ++r) {
      float v = lsum[fn][r];
#pragma unroll
      for (int x = 1; x < 16; x <<= 1) v += __shfl_xor(v, x, 64);
      lsum[fn][r] = v;
    }
  if (lr == 0) {
#pragma unroll
    for (int fn = 0; fn < 2; ++fn)
#pragma unroll
      for (int r = 0; r < 4; ++r) Lbuf[w][fn * 16 + lg * 4 + r] = lsum[fn][r];
  }
#pragma unroll
  for (int fn = 0; fn < 2; ++fn)
#pragma unroll
    for (int df = 0; df < 4; ++df)
#pragma unroll
      for (int r = 0; r < 4; ++r)
        Obuf[w][df * 16 + lg * 4 + r][fn * 16 + lr] = oacc[fn][df][r];
  __syncthreads();

  // ---- combine 4 waves, normalize, store Ot[n][c] (coalesced 16B stores)
  const int n = t >> 3;       // 0..31
  const int db = t & 7;       // d block of 8
  float lt = Lbuf[0][n] + Lbuf[1][n] + Lbuf[2][n] + Lbuf[3][n];
  float linv = 1.0f / lt;
  u16x8 o8;
#pragma unroll
  for (int i = 0; i < 8; ++i) {
    int d = db * 8 + i;
    float ov = Obuf[0][d][n] + Obuf[1][d][n] + Obuf[2][d][n] + Obuf[3][d][n];
    o8[i] = f2bf(ov * linv);
  }
  *(u16x8*)(Ot + (qrow0 + n) * 512 + h * 64 + db * 8) = o8;
}

// ---------------------------------------------------------------- out proj
__global__ __launch_bounds__(256) void k_gemm_out(
    const unsigned short* __restrict__ Wo, const unsigned short* __restrict__ Ot,
    const float* __restrict__ bo,
    const float* __restrict__ f0, const float* __restrict__ f1,
    const float* __restrict__ f2, float* __restrict__ out) {
  const int z = blockIdx.z, b = z / 3, f = z % 3;
  const int t = threadIdx.x, w = t >> 6, l = t & 63, lg = l >> 4, lr = l & 15;
  const int wid = blockIdx.x * 4 + w;        // 0..71 = 8 mtiles * 9 ntiles
  const int mt = wid / 9, ntw = wid % 9;
  const int o0 = mt * 64;
  const unsigned short* B = Ot + (b * 1728 + f * 576 + ntw * 64) * 512;

  f32x4 acc[4][4];
#pragma unroll
  for (int fr = 0; fr < 4; ++fr)
#pragma unroll
    for (int fc = 0; fc < 4; ++fc) acc[fr][fc] = (f32x4){0.f, 0.f, 0.f, 0.f};

#pragma unroll 2
  for (int ks = 0; ks < 16; ++ks) {
    const int k0 = ks * 32;
    bf16x8 af[4], bfv[4];
#pragma unroll
    for (int fr = 0; fr < 4; ++fr)
      af[fr] = *(const bf16x8*)(Wo + (o0 + fr * 16 + lr) * 512 + k0 + lg * 8);
#pragma unroll
    for (int fc = 0; fc < 4; ++fc)
      bfv[fc] = *(const bf16x8*)(B + (fc * 16 + lr) * 512 + k0 + lg * 8);
#pragma unroll
    for (int fr = 0; fr < 4; ++fr)
#pragma unroll
      for (int fc = 0; fc < 4; ++fc)
        acc[fr][fc] = MFMA16(af[fr], bfv[fc], acc[fr][fc]);
  }

  const float* ft = f == 0 ? f0 : f == 1 ? f1 : f2;
#pragma unroll
  for (int fr = 0; fr < 4; ++fr) {
    f32x4 b4 = *(const f32x4*)(bo + o0 + fr * 16 + lg * 4);
#pragma unroll
    for (int fc = 0; fc < 4; ++fc) {
      int ncol = ntw * 64 + fc * 16 + lr;
#pragma unroll
      for (int r = 0; r < 4; ++r) {
        int o = o0 + fr * 16 + lg * 4 + r;
        out[((f * 4 + b) * 512 + o) * 576 + ncol] =
            acc[fr][fc][r] + b4[r] + ft[(b * 512 + o) * 576 + ncol];
      }
    }
  }
}

// ---------------------------------------------------------------- launcher
extern "C" void kernel_launch(void* const* d_in, const int* in_sizes, int n_in,
                              void* d_out, int out_size, void* d_ws, size_t ws_size,
                              hipStream_t stream) {
  const float* f0 = (const float*)d_in[0];
  const float* f1 = (const float*)d_in[1];
  const float* f2 = (const float*)d_in[2];
  const float* Wq = (const float*)d_in[3];
  const float* bq = (const float*)d_in[4];
  const float* Wk = (const float*)d_in[5];
  const float* bk = (const float*)d_in[6];
  const float* Wv = (const float*)d_in[7];
  const float* bv = (const float*)d_in[8];
  const float* Wo = (const float*)d_in[9];
  const float* bo = (const float*)d_in[10];
  float* out = (float*)d_out;

  char* ws = (char*)d_ws;
  unsigned short* Wb = (unsigned short*)(ws);
  unsigned short* Xt = (unsigned short*)(ws + 2097152);
  unsigned short* Qt = (unsigned short*)(ws + 9175040);
  unsigned short* Kt = (unsigned short*)(ws + 16252928);
  unsigned short* Vn = (unsigned short*)(ws + 23330816);
  unsigned short* Ot = Xt;  // Xt is dead after k_gemm_qkv; reuse for attention out

  k_cvt_w<<<1024, 256, 0, stream>>>(Wq, Wk, Wv, Wo, Wb);
  k_pack_xt<<<dim3(9, 8, 12), 256, 0, stream>>>(f0, f1, f2, Xt);
  k_gemm_qkv<<<dim3(54, 1, 12), 256, 0, stream>>>(Wb, Xt, bq, bk, bv, Qt, Kt, Vn);
  k_attn<<<dim3(18, 24, 4), 256, 0, stream>>>(Qt, Kt, Vn, Ot);
  k_gemm_out<<<dim3(18, 1, 12), 256, 0, stream>>>(Wb + 3 * 262144, Ot, bo,
                                                  f0, f1, f2, out);
}

// Round 2
// 190.877 us; speedup vs baseline: 1.0398x; 1.0398x over previous
//
#include <hip/hip_runtime.h>

// ManifoldCrossAttention on MI355X (gfx950), bf16 MFMA pipeline, f32 I/O.
//
// Pipeline (5 kernels, all on `stream`):
//  1. k_cvt_w   : Wq/Wk/Wv/Wo f32 -> bf16 (row-major = K-contiguous for A-frags)
//  2. k_pack_xt : feats [b][c][n] f32 -> Xt [b][m=f*576+n][c] bf16 (K-contig B operand)
//  3. k_gemm_qkv: Q=WqX, K=WkX, V=WvX.  Q,K stored transposed [m][c]; V natural [c][m]
//  4. k_attn    : NEW (round 2): swapped QK^T via 32x32x16 MFMA; P stays in
//                 registers (cvt_pk + shfl_xor(32) redistribution, no LDS in the
//                 main loop, no barriers). 4 waves split KV, LDS combine epilogue.
//  5. k_gemm_out: out = Wo @ O + bo + feat (residual), f32 stores to d_out
//
// Workspace layout (bytes):           size
//   Wb  @ 0         4*512*512*2   = 2097152
//   Xt  @ 2097152   4*1728*512*2  = 7077888   (aliased by Ot after attn)
//   Qt  @ 9175040   7077888
//   Kt  @ 16252928  7077888
//   Vn  @ 23330816  7077888       total 30408704 B

using bf16x8 = __attribute__((ext_vector_type(8))) short;           // 8 bf16 = 4 VGPR
using f32x4  = __attribute__((ext_vector_type(4))) float;
using f32x16 = __attribute__((ext_vector_type(16))) float;
using u32x4  = __attribute__((ext_vector_type(4))) unsigned int;
using u16x4  = __attribute__((ext_vector_type(4))) unsigned short;
using u16x8  = __attribute__((ext_vector_type(8))) unsigned short;

#define MFMA16(a, b, c) __builtin_amdgcn_mfma_f32_16x16x32_bf16((a), (b), (c), 0, 0, 0)
#define MFMA32(a, b, c) __builtin_amdgcn_mfma_f32_32x32x16_bf16((a), (b), (c), 0, 0, 0)

__device__ __forceinline__ unsigned short f2bf(float f) {
  unsigned int u = __float_as_uint(f);
  return (unsigned short)((u + 0x7fffu + ((u >> 16) & 1u)) >> 16);  // RNE
}

__device__ __forceinline__ f32x16 zero16() {
  f32x16 z;
#pragma unroll
  for (int i = 0; i < 16; ++i) z[i] = 0.f;
  return z;
}

// ---------------------------------------------------------------- weights cvt
__global__ __launch_bounds__(256) void k_cvt_w(
    const float* __restrict__ Wq, const float* __restrict__ Wk,
    const float* __restrict__ Wv, const float* __restrict__ Wo,
    unsigned short* __restrict__ Wb) {
  int i   = blockIdx.x * 256 + threadIdx.x;  // 1024 blocks * 256 thr * 4 elem = 4*512*512
  int idx = i * 4;
  int sel = idx >> 18;                       // 262144 elems per matrix
  const float* s = sel == 0 ? Wq : sel == 1 ? Wk : sel == 2 ? Wv : Wo;
  f32x4 v = *(const f32x4*)(s + (idx & 262143));
  u16x4 o;
  o[0] = f2bf(v[0]); o[1] = f2bf(v[1]); o[2] = f2bf(v[2]); o[3] = f2bf(v[3]);
  *(u16x4*)(Wb + idx) = o;
}

// ------------------------------------------------------- pack X^T (transpose)
__global__ __launch_bounds__(256) void k_pack_xt(
    const float* __restrict__ f0, const float* __restrict__ f1,
    const float* __restrict__ f2, unsigned short* __restrict__ Xt) {
  const int nt = blockIdx.x;            // 0..8  (n tile of 64)
  const int ct = blockIdx.y;            // 0..7  (c tile of 64)
  const int z  = blockIdx.z;            // b*3+f
  const int b = z / 3, f = z % 3;
  const int t = threadIdx.x;
  const float* src = (f == 0 ? f0 : f == 1 ? f1 : f2) + b * (512 * 576);

  __shared__ unsigned short tile[64][65];  // +1 pad breaks bank conflicts on read
#pragma unroll
  for (int i = 0; i < 16; ++i) {
    int idx = i * 256 + t;
    int cc = idx >> 6, nn = idx & 63;    // coalesced over nn
    tile[cc][nn] = f2bf(src[(ct * 64 + cc) * 576 + nt * 64 + nn]);
  }
  __syncthreads();
  const int row0 = b * 1728 + f * 576 + nt * 64;
#pragma unroll
  for (int i = 0; i < 16; ++i) {
    int idx = i * 256 + t;
    int nn = idx >> 6, cc = idx & 63;    // coalesced over cc
    Xt[(row0 + nn) * 512 + ct * 64 + cc] = tile[cc][nn];
  }
}

// ---------------------------------------------------------------- QKV GEMM
// C[o][m] = sum_c W[o][c] * Xt[m][c]  (+bias).  Per-wave 64x64 tile, 4x4 frags,
// fragments loaded directly from global (all K-contiguous, 16B per lane).
__global__ __launch_bounds__(256) void k_gemm_qkv(
    const unsigned short* __restrict__ Wb, const unsigned short* __restrict__ Xt,
    const float* __restrict__ bq, const float* __restrict__ bk,
    const float* __restrict__ bv,
    unsigned short* __restrict__ Qt, unsigned short* __restrict__ Kt,
    unsigned short* __restrict__ Vn) {
  const int z = blockIdx.z, b = z / 3, p = z % 3;
  const int t = threadIdx.x, w = t >> 6, l = t & 63, lg = l >> 4, lr = l & 15;
  const int wid = blockIdx.x * 4 + w;          // 0..215 = 8 mtiles * 27 ntiles
  const int mt = wid / 27, ntw = wid % 27;
  const int o0 = mt * 64;
  const unsigned short* A = Wb + p * (512 * 512);
  const unsigned short* B = Xt + (b * 1728 + ntw * 64) * 512;

  f32x4 acc[4][4];
#pragma unroll
  for (int fr = 0; fr < 4; ++fr)
#pragma unroll
    for (int fc = 0; fc < 4; ++fc) acc[fr][fc] = (f32x4){0.f, 0.f, 0.f, 0.f};

#pragma unroll 2
  for (int ks = 0; ks < 16; ++ks) {
    const int k0 = ks * 32;
    bf16x8 af[4], bfv[4];
#pragma unroll
    for (int fr = 0; fr < 4; ++fr)
      af[fr] = *(const bf16x8*)(A + (o0 + fr * 16 + lr) * 512 + k0 + lg * 8);
#pragma unroll
    for (int fc = 0; fc < 4; ++fc)
      bfv[fc] = *(const bf16x8*)(B + (fc * 16 + lr) * 512 + k0 + lg * 8);
#pragma unroll
    for (int fr = 0; fr < 4; ++fr)
#pragma unroll
      for (int fc = 0; fc < 4; ++fc)
        acc[fr][fc] = MFMA16(af[fr], bfv[fc], acc[fr][fc]);
  }

  const float* bias = p == 0 ? bq : p == 1 ? bk : bv;
#pragma unroll
  for (int fr = 0; fr < 4; ++fr) {
    f32x4 b4 = *(const f32x4*)(bias + o0 + fr * 16 + lg * 4);
#pragma unroll
    for (int fc = 0; fc < 4; ++fc) {
      if (p < 2) {  // Q,K stored transposed: [b*1728+m][o]
        unsigned short* outT = (p == 0) ? Qt : Kt;
        int mrow = b * 1728 + ntw * 64 + fc * 16 + lr;
        u16x4 pk;
#pragma unroll
        for (int r = 0; r < 4; ++r) pk[r] = f2bf(acc[fr][fc][r] + b4[r]);
        *(u16x4*)(outT + mrow * 512 + o0 + fr * 16 + lg * 4) = pk;
      } else {      // V natural: [b*512+o][m]
        int mcol = ntw * 64 + fc * 16 + lr;
#pragma unroll
        for (int r = 0; r < 4; ++r) {
          int o = o0 + fr * 16 + lg * 4 + r;
          Vn[(b * 512 + o) * 1728 + mcol] = f2bf(acc[fr][fc][r] + b4[r]);
        }
      }
    }
  }
}

// ---------------------------------------------------------------- attention
// Block = one (b, h, 32 q-rows) tile; 4 waves split the 54 KV-steps of 32.
// Swapped QK^T: S^T = mfma32(A=K, B=Q) -> lane owns q-col n = l&31 for both
// S^T and the PV A-operand row. P never touches LDS:
//   p[r] (r=0..15) at lane: m = (r&3)+8*(r>>2)+4*hi, n = l&31.
//   words W[u] = cvt_pk(p[2u], p[2u+1]) hold m-pair at 8*(u>>1)+4*hi+2*(u&1).
//   PV A-frag word j2 of k-frag kf must be W[4*kf+2*hi_t+(j2&1)] taken from
//   lane half (j2>>1)  => per (kf,w): 1 cndmask + 1 shfl_xor(32) + 2 cndmask.
// No-max softmax (scores ~N(0,0.2^2)): p = exp(s/8); per-lane scalar row-sum.
__global__ __launch_bounds__(256) void k_attn(
    const unsigned short* __restrict__ Qt, const unsigned short* __restrict__ Kt,
    const unsigned short* __restrict__ V, unsigned short* __restrict__ Ot) {
  const int tile = blockIdx.x;               // 0..53 (32 q-rows each; 54*32=1728)
  const int h    = blockIdx.y;               // 0..7
  const int b    = blockIdx.z;               // 0..3
  const int t = threadIdx.x, w = t >> 6, l = t & 63;
  const int lr = l & 31, hi = l >> 5;
  const int qrow0 = b * 1728 + tile * 32;

  __shared__ float Obuf[4][32][68];          // partial O per wave, [n][d], pad 68
  __shared__ float Lbuf[4][32];              // partial row-sums per wave

  const unsigned short* Qb = Qt + (qrow0 + lr) * 512 + h * 64 + hi * 8;
  const unsigned short* Kb = Kt + (b * 1728 + lr) * 512 + h * 64 + hi * 8;
  const unsigned short* Vb = V + (b * 512 + h * 64 + lr) * 1728 + hi * 8;

  // Q B-frags (hoisted): col n = lr, k = d = kf*16 + hi*8 + j
  bf16x8 bq[4];
#pragma unroll
  for (int kf = 0; kf < 4; ++kf) bq[kf] = *(const bf16x8*)(Qb + kf * 16);

  f32x16 oacc[2];
  oacc[0] = zero16();
  oacc[1] = zero16();
  float lsum = 0.f;

  for (int sm = w; sm < 54; sm += 4) {
    const int m0 = sm * 32;
    // ---- K A-frags: row m = m0 + lr, k = d
    bf16x8 ak[4];
#pragma unroll
    for (int kf = 0; kf < 4; ++kf)
      ak[kf] = *(const bf16x8*)(Kb + m0 * 512 + kf * 16);
    // ---- V B-frags for PV: col d = dt*32 + lr, k = m = m0 + kf2*16 + hi*8 + j
    bf16x8 vbf[2][2];
#pragma unroll
    for (int dt = 0; dt < 2; ++dt)
#pragma unroll
      for (int kf2 = 0; kf2 < 2; ++kf2)
        vbf[dt][kf2] = *(const bf16x8*)(Vb + dt * 55296 + m0 + kf2 * 16);

    // ---- S^T = K Q^T over d=64 (4 chained mfma32 k=16)
    f32x16 sfr = zero16();
#pragma unroll
    for (int kf = 0; kf < 4; ++kf) sfr = MFMA32(ak[kf], bq[kf], sfr);

    // ---- p = exp(s/8), per-lane row-sum (n = lr fixed per lane)
    float pv[16];
    float ls0 = 0.f, ls1 = 0.f;
#pragma unroll
    for (int r = 0; r < 16; ++r) {
      pv[r] = __expf(sfr[r] * 0.125f);
      if (r & 1) ls1 += pv[r]; else ls0 += pv[r];
    }
    lsum += ls0 + ls1;

    // ---- pack to bf16 pairs (m-adjacent): W[u] holds m = 8*(u>>1)+4*hi+2*(u&1)
    unsigned int W[8];
#pragma unroll
    for (int u = 0; u < 8; ++u)
      asm("v_cvt_pk_bf16_f32 %0, %1, %2"
          : "=v"(W[u]) : "v"(pv[2 * u]), "v"(pv[2 * u + 1]));

    // ---- redistribute to PV A-frags (pure in-register, one shfl_xor each)
    unsigned int fw[2][4];
#pragma unroll
    for (int kf = 0; kf < 2; ++kf)
#pragma unroll
      for (int wd = 0; wd < 2; ++wd) {
        unsigned int lo  = W[4 * kf + wd];
        unsigned int hw  = W[4 * kf + 2 + wd];
        unsigned int pub = hi ? lo : hw;
        unsigned int rcv = (unsigned int)__shfl_xor((int)pub, 32, 64);
        fw[kf][wd]     = hi ? rcv : lo;
        fw[kf][2 + wd] = hi ? hw : rcv;
      }

    // ---- PV: O[n][d] += P[n][m] V[m][d]
#pragma unroll
    for (int kf2 = 0; kf2 < 2; ++kf2) {
      u32x4 fv;
      fv[0] = fw[kf2][0]; fv[1] = fw[kf2][1];
      fv[2] = fw[kf2][2]; fv[3] = fw[kf2][3];
      bf16x8 pa = __builtin_bit_cast(bf16x8, fv);
#pragma unroll
      for (int dt = 0; dt < 2; ++dt)
        oacc[dt] = MFMA32(pa, vbf[dt][kf2], oacc[dt]);
    }
  }

  // ---- write per-wave partials (D layout: col d = lr, row n = (r&3)+8*(r>>2)+4*hi)
#pragma unroll
  for (int dt = 0; dt < 2; ++dt)
#pragma unroll
    for (int r = 0; r < 16; ++r)
      Obuf[w][(r & 3) + 8 * (r >> 2) + 4 * hi][dt * 32 + lr] = oacc[dt][r];
  float ltot = lsum + __shfl_xor(lsum, 32, 64);   // both halves of row n = lr
  if (l < 32) Lbuf[w][lr] = ltot;
  __syncthreads();

  // ---- combine 4 waves, normalize, store Ot[n][c] (coalesced 16B stores)
  const int n = t >> 3;       // 0..31
  const int d0 = (t & 7) * 8; // d block of 8
  float lt = Lbuf[0][n] + Lbuf[1][n] + Lbuf[2][n] + Lbuf[3][n];
  float linv = 1.0f / lt;
  u16x8 o8;
#pragma unroll
  for (int i = 0; i < 8; ++i) {
    float ov = Obuf[0][n][d0 + i] + Obuf[1][n][d0 + i] +
               Obuf[2][n][d0 + i] + Obuf[3][n][d0 + i];
    o8[i] = f2bf(ov * linv);
  }
  *(u16x8*)(Ot + (qrow0 + n) * 512 + h * 64 + d0) = o8;
}

// ---------------------------------------------------------------- out proj
__global__ __launch_bounds__(256) void k_gemm_out(
    const unsigned short* __restrict__ Wo, const unsigned short* __restrict__ Ot,
    const float* __restrict__ bo,
    const float* __restrict__ f0, const float* __restrict__ f1,
    const float* __restrict__ f2, float* __restrict__ out) {
  const int z = blockIdx.z, b = z / 3, f = z % 3;
  const int t = threadIdx.x, w = t >> 6, l = t & 63, lg = l >> 4, lr = l & 15;
  const int wid = blockIdx.x * 4 + w;        // 0..71 = 8 mtiles * 9 ntiles
  const int mt = wid / 9, ntw = wid % 9;
  const int o0 = mt * 64;
  const unsigned short* B = Ot + (b * 1728 + f * 576 + ntw * 64) * 512;

  f32x4 acc[4][4];
#pragma unroll
  for (int fr = 0; fr < 4; ++fr)
#pragma unroll
    for (int fc = 0; fc < 4; ++fc) acc[fr][fc] = (f32x4){0.f, 0.f, 0.f, 0.f};

#pragma unroll 2
  for (int ks = 0; ks < 16; ++ks) {
    const int k0 = ks * 32;
    bf16x8 af[4], bfv[4];
#pragma unroll
    for (int fr = 0; fr < 4; ++fr)
      af[fr] = *(const bf16x8*)(Wo + (o0 + fr * 16 + lr) * 512 + k0 + lg * 8);
#pragma unroll
    for (int fc = 0; fc < 4; ++fc)
      bfv[fc] = *(const bf16x8*)(B + (fc * 16 + lr) * 512 + k0 + lg * 8);
#pragma unroll
    for (int fr = 0; fr < 4; ++fr)
#pragma unroll
      for (int fc = 0; fc < 4; ++fc)
        acc[fr][fc] = MFMA16(af[fr], bfv[fc], acc[fr][fc]);
  }

  const float* ft = f == 0 ? f0 : f == 1 ? f1 : f2;
#pragma unroll
  for (int fr = 0; fr < 4; ++fr) {
    f32x4 b4 = *(const f32x4*)(bo + o0 + fr * 16 + lg * 4);
#pragma unroll
    for (int fc = 0; fc < 4; ++fc) {
      int ncol = ntw * 64 + fc * 16 + lr;
#pragma unroll
      for (int r = 0; r < 4; ++r) {
        int o = o0 + fr * 16 + lg * 4 + r;
        out[((f * 4 + b) * 512 + o) * 576 + ncol] =
            acc[fr][fc][r] + b4[r] + ft[(b * 512 + o) * 576 + ncol];
      }
    }
  }
}

// ---------------------------------------------------------------- launcher
extern "C" void kernel_launch(void* const* d_in, const int* in_sizes, int n_in,
                              void* d_out, int out_size, void* d_ws, size_t ws_size,
                              hipStream_t stream) {
  const float* f0 = (const float*)d_in[0];
  const float* f1 = (const float*)d_in[1];
  const float* f2 = (const float*)d_in[2];
  const float* Wq = (const float*)d_in[3];
  const float* bq = (const float*)d_in[4];
  const float* Wk = (const float*)d_in[5];
  const float* bk = (const float*)d_in[6];
  const float* Wv = (const float*)d_in[7];
  const float* bv = (const float*)d_in[8];
  const float* Wo = (const float*)d_in[9];
  const float* bo = (const float*)d_in[10];
  float* out = (float*)d_out;

  char* ws = (char*)d_ws;
  unsigned short* Wb = (unsigned short*)(ws);
  unsigned short* Xt = (unsigned short*)(ws + 2097152);
  unsigned short* Qt = (unsigned short*)(ws + 9175040);
  unsigned short* Kt = (unsigned short*)(ws + 16252928);
  unsigned short* Vn = (unsigned short*)(ws + 23330816);
  unsigned short* Ot = Xt;  // Xt is dead after k_gemm_qkv; reuse for attention out

  k_cvt_w<<<1024, 256, 0, stream>>>(Wq, Wk, Wv, Wo, Wb);
  k_pack_xt<<<dim3(9, 8, 12), 256, 0, stream>>>(f0, f1, f2, Xt);
  k_gemm_qkv<<<dim3(54, 1, 12), 256, 0, stream>>>(Wb, Xt, bq, bk, bv, Qt, Kt, Vn);
  k_attn<<<dim3(54, 8, 4), 256, 0, stream>>>(Qt, Kt, Vn, Ot);
  k_gemm_out<<<dim3(18, 1, 12), 256, 0, stream>>>(Wb + 3 * 262144, Ot, bo,
                                                  f0, f1, f2, out);
}

// Round 3
// 109.249 us; speedup vs baseline: 1.8167x; 1.7472x over previous
//
#include <hip/hip_runtime.h>

// ManifoldCrossAttention on MI355X (gfx950), bf16 MFMA pipeline, f32 I/O.
//
// Round 3: ALL MFMA operands stored in pre-fragmented layout — the 16B each
// lane loads for a fragment sits at chunk_base + lane*16B, so every fragment
// load is 1KB fully contiguous (16 cachelines, 100% utilization) instead of
// 64 scattered lines. Attention processes 2 q-tiles per wave (halves K/V
// logical traffic).
//
// Fragment layouts (bf16 element offsets):
//  Wf [p][mt=8][ks=16][fr=4][lane=64][8]   : W[o=mt*64+fr*16+(l&15)][c=ks*32+(l>>4)*8+j]
//  Xf [b][ntw=27][ks=16][fc=4][lane][8]    : X[m=ntw*64+fc*16+(l&15)][c=ks*32+(l>>4)*8+j]
//  Qf/Kf [bh=32][ck=54][kf=4][lane][8]     : M[row=ck*32+(l&31)][d=kf*16+(l>>5)*8+j]
//  Vf [bh][ck=54][dt=2][kf2=2][lane][8]    : V[d=dt*32+(l&31)][m=ck*32+kf2*16+(l>>5)*8+j]
//  Of — same as Xf (consumed by k_gemm_out as B operand)
//
// Workspace: Wf@0 (2MB), Xf/Of@2097152 (7MB), Qf@9175040, Kf@16252928,
//            Vf@23330816 — total 30408704 B.

using bf16x8 = __attribute__((ext_vector_type(8))) short;
using f32x4  = __attribute__((ext_vector_type(4))) float;
using f32x16 = __attribute__((ext_vector_type(16))) float;
using u32x4  = __attribute__((ext_vector_type(4))) unsigned int;
using u16x4  = __attribute__((ext_vector_type(4))) unsigned short;
using u16x8  = __attribute__((ext_vector_type(8))) unsigned short;

#define MFMA16(a, b, c) __builtin_amdgcn_mfma_f32_16x16x32_bf16((a), (b), (c), 0, 0, 0)
#define MFMA32(a, b, c) __builtin_amdgcn_mfma_f32_32x32x16_bf16((a), (b), (c), 0, 0, 0)

__device__ __forceinline__ unsigned short f2bf(float f) {
  unsigned int u = __float_as_uint(f);
  return (unsigned short)((u + 0x7fffu + ((u >> 16) & 1u)) >> 16);  // RNE
}

__device__ __forceinline__ f32x16 zero16() {
  f32x16 z;
#pragma unroll
  for (int i = 0; i < 16; ++i) z[i] = 0.f;
  return z;
}

// ---------------------------------------------------------------- weights cvt
// f32 [p][o][c] -> Wf fragments.
__global__ __launch_bounds__(256) void k_cvt_w(
    const float* __restrict__ Wq, const float* __restrict__ Wk,
    const float* __restrict__ Wv, const float* __restrict__ Wo,
    unsigned short* __restrict__ Wf) {
  int i   = blockIdx.x * 256 + threadIdx.x;
  int idx = i * 4;
  int p   = idx >> 18;
  int rem = idx & 262143;
  int o = rem >> 9, c0 = rem & 511;
  const float* s = p == 0 ? Wq : p == 1 ? Wk : p == 2 ? Wv : Wo;
  f32x4 v = *(const f32x4*)(s + rem);
  u16x4 pk;
  pk[0] = f2bf(v[0]); pk[1] = f2bf(v[1]); pk[2] = f2bf(v[2]); pk[3] = f2bf(v[3]);
  int mt = o >> 6, fr = (o & 63) >> 4, lr = o & 15;
  int ks = c0 >> 5, lg = (c0 & 31) >> 3, j0 = c0 & 7;  // j0 in {0,4}
  size_t off = (size_t)((((p * 8 + mt) * 16 + ks) * 4 + fr)) * 512 +
               (lg * 16 + lr) * 8 + j0;
  *(u16x4*)(Wf + off) = pk;
}

// ------------------------------------------------------- pack X fragments
__global__ __launch_bounds__(256) void k_pack_xt(
    const float* __restrict__ f0, const float* __restrict__ f1,
    const float* __restrict__ f2, unsigned short* __restrict__ Xf) {
  const int nt = blockIdx.x;            // 0..8  (n tile of 64)
  const int ct = blockIdx.y;            // 0..7  (c tile of 64)
  const int z  = blockIdx.z;            // b*3+f
  const int b = z / 3, f = z % 3;
  const int t = threadIdx.x;
  const float* src = (f == 0 ? f0 : f == 1 ? f1 : f2) + b * (512 * 576);

  __shared__ unsigned short tile[64][65];  // [c_local][n_local]
#pragma unroll
  for (int i = 0; i < 16; ++i) {
    int idx = i * 256 + t;
    int cc = idx >> 6, nn = idx & 63;    // coalesced over nn
    tile[cc][nn] = f2bf(src[(ct * 64 + cc) * 576 + nt * 64 + nn]);
  }
  __syncthreads();
  const int ntw = f * 9 + nt;            // global m-tile (0..26)
#pragma unroll
  for (int i = 0; i < 4; ++i) {
    int slot = i * 256 + t;              // 1024 slots: [nn=64][cquad=16]
    int nn = slot >> 4, cq = slot & 15;
    int cl = cq * 4;                     // c_local
    int c  = ct * 64 + cl;
    int fc = nn >> 4, lr = nn & 15;
    int ks = c >> 5, lg = (c & 31) >> 3, j0 = c & 7;
    u16x4 pk;
    pk[0] = tile[cl][nn]; pk[1] = tile[cl + 1][nn];
    pk[2] = tile[cl + 2][nn]; pk[3] = tile[cl + 3][nn];
    size_t off = (size_t)((((b * 27 + ntw) * 16 + ks) * 4 + fc)) * 512 +
                 (lg * 16 + lr) * 8 + j0;
    *(u16x4*)(Xf + off) = pk;
  }
}

// ---------------------------------------------------------------- QKV GEMM
// C[o][m] = sum_c W[o][c]*X[m][c] + bias. Frag loads fully contiguous.
// Epilogue scatters into Qf/Kf (8B vec) or Vf (scalar) fragment layouts.
__global__ __launch_bounds__(256) void k_gemm_qkv(
    const unsigned short* __restrict__ Wf, const unsigned short* __restrict__ Xf,
    const float* __restrict__ bq, const float* __restrict__ bk,
    const float* __restrict__ bv,
    unsigned short* __restrict__ Qf, unsigned short* __restrict__ Kf,
    unsigned short* __restrict__ Vf) {
  const int z = blockIdx.z, b = z / 3, p = z % 3;
  const int t = threadIdx.x, w = t >> 6, l = t & 63, lg = l >> 4, lr = l & 15;
  const int wid = blockIdx.x * 4 + w;          // 0..215 = 8 mtiles * 27 ntiles
  const int mt = wid / 27, ntw = wid % 27;
  const unsigned short* A = Wf + (size_t)(p * 8 + mt) * 16 * 2048 + l * 8;
  const unsigned short* B = Xf + (size_t)(b * 27 + ntw) * 16 * 2048 + l * 8;

  f32x4 acc[4][4];
#pragma unroll
  for (int fr = 0; fr < 4; ++fr)
#pragma unroll
    for (int fc = 0; fc < 4; ++fc) acc[fr][fc] = (f32x4){0.f, 0.f, 0.f, 0.f};

#pragma unroll 2
  for (int ks = 0; ks < 16; ++ks) {
    bf16x8 af[4], bfv[4];
#pragma unroll
    for (int fr = 0; fr < 4; ++fr)
      af[fr] = *(const bf16x8*)(A + ks * 2048 + fr * 512);
#pragma unroll
    for (int fc = 0; fc < 4; ++fc)
      bfv[fc] = *(const bf16x8*)(B + ks * 2048 + fc * 512);
#pragma unroll
    for (int fr = 0; fr < 4; ++fr)
#pragma unroll
      for (int fc = 0; fc < 4; ++fc)
        acc[fr][fc] = MFMA16(af[fr], bfv[fc], acc[fr][fc]);
  }

  const float* bias = p == 0 ? bq : p == 1 ? bk : bv;
  const int bh = b * 8 + mt;  // o0 = mt*64 -> head = mt, d = o&63
#pragma unroll
  for (int fr = 0; fr < 4; ++fr) {
    f32x4 b4 = *(const f32x4*)(bias + mt * 64 + fr * 16 + lg * 4);
#pragma unroll
    for (int fc = 0; fc < 4; ++fc) {
      int ck = ntw * 2 + (fc >> 1);
      if (p < 2) {
        // d = fr*16+lg*4+r -> kf=fr, hi=lg>>1, j=(lg&1)*4+r ; row slot=(fc&1)*16+lr
        unsigned short* outF = (p == 0) ? Qf : Kf;
        u16x4 pk;
#pragma unroll
        for (int r = 0; r < 4; ++r) pk[r] = f2bf(acc[fr][fc][r] + b4[r]);
        size_t off = ((size_t)bh * 54 + ck) * 2048 + fr * 512 +
                     ((lg >> 1) * 32 + (fc & 1) * 16 + lr) * 8 + (lg & 1) * 4;
        *(u16x4*)(outF + off) = pk;
      } else {
        // V: d=fr*16+lg*4+r -> dt=fr>>1, dlane=(fr&1)*16+lg*4+r;
        //    m=ntw*64+fc*16+lr -> kf2=fc&1, hi=(lr>>3)&1, j=lr&7
        size_t base = ((size_t)bh * 54 + ck) * 2048 +
                      ((fr >> 1) * 2 + (fc & 1)) * 512 +
                      (((lr >> 3) & 1) * 32 + (fr & 1) * 16 + lg * 4) * 8 +
                      (lr & 7);
#pragma unroll
        for (int r = 0; r < 4; ++r)
          Vf[base + r * 8] = f2bf(acc[fr][fc][r] + b4[r]);
      }
    }
  }
}

// ---------------------------------------------------------------- attention
// Block = (g, h, b): 2 q-tiles (t0=2g, t1=2g+1) shared by 4 waves; waves split
// the 54 KV chunks 4-ways; per chunk both tiles are processed (K/V read once
// serves 64 q-rows). Swapped QK^T (mfma32), P in registers via cvt_pk +
// shfl_xor(32). No-max softmax (scores tiny). LDS combine epilogue, 2 passes.
__device__ __forceinline__ void attn_tile(const f32x16& s, float& lsum,
                                          f32x16 oacc[2],
                                          const bf16x8 vbf[2][2], int hi) {
  float pv[16];
  float a0 = 0.f, a1 = 0.f;
#pragma unroll
  for (int r = 0; r < 16; ++r) {
    pv[r] = __expf(s[r] * 0.125f);
    if (r & 1) a1 += pv[r]; else a0 += pv[r];
  }
  lsum += a0 + a1;
  unsigned int W[8];
#pragma unroll
  for (int u = 0; u < 8; ++u)
    asm("v_cvt_pk_bf16_f32 %0, %1, %2"
        : "=v"(W[u]) : "v"(pv[2 * u]), "v"(pv[2 * u + 1]));
  unsigned int fw[2][4];
#pragma unroll
  for (int kf = 0; kf < 2; ++kf)
#pragma unroll
    for (int wd = 0; wd < 2; ++wd) {
      unsigned int lo  = W[4 * kf + wd];
      unsigned int hw  = W[4 * kf + 2 + wd];
      unsigned int pub = hi ? lo : hw;
      unsigned int rcv = (unsigned int)__shfl_xor((int)pub, 32, 64);
      fw[kf][wd]     = hi ? rcv : lo;
      fw[kf][2 + wd] = hi ? hw : rcv;
    }
#pragma unroll
  for (int kf2 = 0; kf2 < 2; ++kf2) {
    u32x4 fv;
    fv[0] = fw[kf2][0]; fv[1] = fw[kf2][1];
    fv[2] = fw[kf2][2]; fv[3] = fw[kf2][3];
    bf16x8 pa = __builtin_bit_cast(bf16x8, fv);
#pragma unroll
    for (int dt = 0; dt < 2; ++dt)
      oacc[dt] = MFMA32(pa, vbf[dt][kf2], oacc[dt]);
  }
}

__global__ __launch_bounds__(256) void k_attn(
    const unsigned short* __restrict__ Qf, const unsigned short* __restrict__ Kf,
    const unsigned short* __restrict__ Vf, unsigned short* __restrict__ Of) {
  const int g = blockIdx.x;                  // 0..26 -> tiles 2g, 2g+1
  const int h = blockIdx.y;                  // 0..7
  const int b = blockIdx.z;                  // 0..3
  const int bh = b * 8 + h;
  const int t = threadIdx.x, w = t >> 6, l = t & 63;
  const int lr = l & 31, hi = l >> 5;
  const int t0 = g * 2, t1 = g * 2 + 1;

  __shared__ float Obuf[4][32][68];
  __shared__ float Lbuf[4][2][32];

  const unsigned short* Qb0 = Qf + ((size_t)bh * 54 + t0) * 2048 + l * 8;
  const unsigned short* Qb1 = Qf + ((size_t)bh * 54 + t1) * 2048 + l * 8;
  bf16x8 bq0[4], bq1[4];
#pragma unroll
  for (int kf = 0; kf < 4; ++kf) {
    bq0[kf] = *(const bf16x8*)(Qb0 + kf * 512);
    bq1[kf] = *(const bf16x8*)(Qb1 + kf * 512);
  }

  f32x16 o0acc[2], o1acc[2];
  o0acc[0] = zero16(); o0acc[1] = zero16();
  o1acc[0] = zero16(); o1acc[1] = zero16();
  float ls0 = 0.f, ls1 = 0.f;

  const unsigned short* Kb = Kf + (size_t)bh * 54 * 2048 + l * 8;
  const unsigned short* Vb = Vf + (size_t)bh * 54 * 2048 + l * 8;

  for (int ck = w; ck < 54; ck += 4) {
    const unsigned short* kc = Kb + ck * 2048;
    const unsigned short* vc = Vb + ck * 2048;
    bf16x8 ak[4];
#pragma unroll
    for (int kf = 0; kf < 4; ++kf) ak[kf] = *(const bf16x8*)(kc + kf * 512);
    bf16x8 vbf[2][2];
#pragma unroll
    for (int dt = 0; dt < 2; ++dt)
#pragma unroll
      for (int kf2 = 0; kf2 < 2; ++kf2)
        vbf[dt][kf2] = *(const bf16x8*)(vc + (dt * 2 + kf2) * 512);

    f32x16 s0 = zero16(), s1 = zero16();
#pragma unroll
    for (int kf = 0; kf < 4; ++kf) s0 = MFMA32(ak[kf], bq0[kf], s0);
#pragma unroll
    for (int kf = 0; kf < 4; ++kf) s1 = MFMA32(ak[kf], bq1[kf], s1);

    attn_tile(s0, ls0, o0acc, vbf, hi);
    attn_tile(s1, ls1, o1acc, vbf, hi);
  }

  // ---- epilogue: two passes through shared combine buffers
  float lt0 = ls0 + __shfl_xor(ls0, 32, 64);
  float lt1 = ls1 + __shfl_xor(ls1, 32, 64);
  if (l < 32) { Lbuf[w][0][lr] = lt0; Lbuf[w][1][lr] = lt1; }
#pragma unroll
  for (int dt = 0; dt < 2; ++dt)
#pragma unroll
    for (int r = 0; r < 16; ++r)
      Obuf[w][(r & 3) + 8 * (r >> 2) + 4 * hi][dt * 32 + lr] = o0acc[dt][r];
  __syncthreads();

  const int n = t >> 3, d0 = (t & 7) * 8;
  {
    float lt = Lbuf[0][0][n] + Lbuf[1][0][n] + Lbuf[2][0][n] + Lbuf[3][0][n];
    float linv = 1.0f / lt;
    u16x8 o8;
#pragma unroll
    for (int i = 0; i < 8; ++i) {
      float ov = Obuf[0][n][d0 + i] + Obuf[1][n][d0 + i] +
                 Obuf[2][n][d0 + i] + Obuf[3][n][d0 + i];
      o8[i] = f2bf(ov * linv);
    }
    size_t off = (size_t)((((b * 27 + (t0 >> 1)) * 16 + h * 2 + (d0 >> 5)) * 4 +
                           (t0 & 1) * 2 + (n >> 4))) * 512 +
                 ((d0 >> 3) & 3) * 128 + (n & 15) * 8;
    *(u16x8*)(Of + off) = o8;
  }
  __syncthreads();
#pragma unroll
  for (int dt = 0; dt < 2; ++dt)
#pragma unroll
    for (int r = 0; r < 16; ++r)
      Obuf[w][(r & 3) + 8 * (r >> 2) + 4 * hi][dt * 32 + lr] = o1acc[dt][r];
  __syncthreads();
  {
    float lt = Lbuf[0][1][n] + Lbuf[1][1][n] + Lbuf[2][1][n] + Lbuf[3][1][n];
    float linv = 1.0f / lt;
    u16x8 o8;
#pragma unroll
    for (int i = 0; i < 8; ++i) {
      float ov = Obuf[0][n][d0 + i] + Obuf[1][n][d0 + i] +
                 Obuf[2][n][d0 + i] + Obuf[3][n][d0 + i];
      o8[i] = f2bf(ov * linv);
    }
    size_t off = (size_t)((((b * 27 + (t1 >> 1)) * 16 + h * 2 + (d0 >> 5)) * 4 +
                           (t1 & 1) * 2 + (n >> 4))) * 512 +
                 ((d0 >> 3) & 3) * 128 + (n & 15) * 8;
    *(u16x8*)(Of + off) = o8;
  }
}

// ---------------------------------------------------------------- out proj
__global__ __launch_bounds__(256) void k_gemm_out(
    const unsigned short* __restrict__ Wf, const unsigned short* __restrict__ Of,
    const float* __restrict__ bo,
    const float* __restrict__ f0, const float* __restrict__ f1,
    const float* __restrict__ f2, float* __restrict__ out) {
  const int z = blockIdx.z, b = z / 3, f = z % 3;
  const int t = threadIdx.x, w = t >> 6, l = t & 63, lg = l >> 4, lr = l & 15;
  const int wid = blockIdx.x * 4 + w;        // 0..71 = 8 mtiles * 9 ntiles
  const int mt = wid / 9, ntw = wid % 9;
  const int o0 = mt * 64;
  const unsigned short* A = Wf + (size_t)(3 * 8 + mt) * 16 * 2048 + l * 8;
  const unsigned short* B = Of + (size_t)(b * 27 + f * 9 + ntw) * 16 * 2048 + l * 8;

  f32x4 acc[4][4];
#pragma unroll
  for (int fr = 0; fr < 4; ++fr)
#pragma unroll
    for (int fc = 0; fc < 4; ++fc) acc[fr][fc] = (f32x4){0.f, 0.f, 0.f, 0.f};

#pragma unroll 2
  for (int ks = 0; ks < 16; ++ks) {
    bf16x8 af[4], bfv[4];
#pragma unroll
    for (int fr = 0; fr < 4; ++fr)
      af[fr] = *(const bf16x8*)(A + ks * 2048 + fr * 512);
#pragma unroll
    for (int fc = 0; fc < 4; ++fc)
      bfv[fc] = *(const bf16x8*)(B + ks * 2048 + fc * 512);
#pragma unroll
    for (int fr = 0; fr < 4; ++fr)
#pragma unroll
      for (int fc = 0; fc < 4; ++fc)
        acc[fr][fc] = MFMA16(af[fr], bfv[fc], acc[fr][fc]);
  }

  const float* ft = f == 0 ? f0 : f == 1 ? f1 : f2;
#pragma unroll
  for (int fr = 0; fr < 4; ++fr) {
    f32x4 b4 = *(const f32x4*)(bo + o0 + fr * 16 + lg * 4);
#pragma unroll
    for (int fc = 0; fc < 4; ++fc) {
      int ncol = ntw * 64 + fc * 16 + lr;
#pragma unroll
      for (int r = 0; r < 4; ++r) {
        int o = o0 + fr * 16 + lg * 4 + r;
        out[((f * 4 + b) * 512 + o) * 576 + ncol] =
            acc[fr][fc][r] + b4[r] + ft[(b * 512 + o) * 576 + ncol];
      }
    }
  }
}

// ---------------------------------------------------------------- launcher
extern "C" void kernel_launch(void* const* d_in, const int* in_sizes, int n_in,
                              void* d_out, int out_size, void* d_ws, size_t ws_size,
                              hipStream_t stream) {
  const float* f0 = (const float*)d_in[0];
  const float* f1 = (const float*)d_in[1];
  const float* f2 = (const float*)d_in[2];
  const float* Wq = (const float*)d_in[3];
  const float* bq = (const float*)d_in[4];
  const float* Wk = (const float*)d_in[5];
  const float* bk = (const float*)d_in[6];
  const float* Wv = (const float*)d_in[7];
  const float* bv = (const float*)d_in[8];
  const float* Wo = (const float*)d_in[9];
  const float* bo = (const float*)d_in[10];
  float* out = (float*)d_out;

  char* ws = (char*)d_ws;
  unsigned short* Wf = (unsigned short*)(ws);
  unsigned short* Xf = (unsigned short*)(ws + 2097152);
  unsigned short* Qf = (unsigned short*)(ws + 9175040);
  unsigned short* Kf = (unsigned short*)(ws + 16252928);
  unsigned short* Vf = (unsigned short*)(ws + 23330816);
  unsigned short* Of = Xf;  // Xf dead after k_gemm_qkv; reused for attention out

  k_cvt_w<<<1024, 256, 0, stream>>>(Wq, Wk, Wv, Wo, Wf);
  k_pack_xt<<<dim3(9, 8, 12), 256, 0, stream>>>(f0, f1, f2, Xf);
  k_gemm_qkv<<<dim3(54, 1, 12), 256, 0, stream>>>(Wf, Xf, bq, bk, bv, Qf, Kf, Vf);
  k_attn<<<dim3(27, 8, 4), 256, 0, stream>>>(Qf, Kf, Vf, Of);
  k_gemm_out<<<dim3(18, 1, 12), 256, 0, stream>>>(Wf, Of, bo, f0, f1, f2, out);
}

// Round 5
// 108.407 us; speedup vs baseline: 1.8308x; 1.0078x over previous
//
#include <hip/hip_runtime.h>

// ManifoldCrossAttention on MI355X (gfx950), bf16 MFMA pipeline, f32 I/O.
//
// Round 5 = verified round-3 compute (shuffle-based P redistribution, identity
// V layout) + two pure bijective grid remaps for XCD/L2 locality:
//   k_attn:     XCD k owns bh in {4k..4k+3} -> per-XCD K/V = 1.8MB < 4MB L2.
//   k_gemm_qkv: XCD k owns b = k>>1, bx parity = k&1 -> per-XCD read set
//               = Wf(1.5MB) + Xf[b](1.75MB) = 3.25MB < 4MB L2.
// (Round 4's sigma-permuted V reverted: failed on HW, root cause unresolved;
//  re-attempt in isolation later if profitable.)
//
// Fragment layouts (bf16 element offsets):
//  Wf [p][mt=8][ks=16][fr=4][lane=64][8]   : W[o=mt*64+fr*16+(l&15)][c=ks*32+(l>>4)*8+j]
//  Xf [b][ntw=27][ks=16][fc=4][lane][8]    : X[m=ntw*64+fc*16+(l&15)][c=ks*32+(l>>4)*8+j]
//  Qf/Kf [bh=32][ck=54][kf=4][lane][8]     : M[row=ck*32+(l&31)][d=kf*16+(l>>5)*8+j]
//  Vf [bh][ck=54][dt=2][kf2=2][lane][8]    : V[d=dt*32+(l&31)][m=ck*32+kf2*16+(l>>5)*8+j]
//  Of -- same as Xf (consumed by k_gemm_out as B operand)
//
// Workspace: Wf@0 (2MB), Xf/Of@2097152 (7MB), Qf@9175040, Kf@16252928,
//            Vf@23330816 -- total 30408704 B.

using bf16x8 = __attribute__((ext_vector_type(8))) short;
using f32x4  = __attribute__((ext_vector_type(4))) float;
using f32x16 = __attribute__((ext_vector_type(16))) float;
using u32x4  = __attribute__((ext_vector_type(4))) unsigned int;
using u16x4  = __attribute__((ext_vector_type(4))) unsigned short;
using u16x8  = __attribute__((ext_vector_type(8))) unsigned short;

#define MFMA16(a, b, c) __builtin_amdgcn_mfma_f32_16x16x32_bf16((a), (b), (c), 0, 0, 0)
#define MFMA32(a, b, c) __builtin_amdgcn_mfma_f32_32x32x16_bf16((a), (b), (c), 0, 0, 0)

__device__ __forceinline__ unsigned short f2bf(float f) {
  unsigned int u = __float_as_uint(f);
  return (unsigned short)((u + 0x7fffu + ((u >> 16) & 1u)) >> 16);  // RNE
}

__device__ __forceinline__ f32x16 zero16() {
  f32x16 z;
#pragma unroll
  for (int i = 0; i < 16; ++i) z[i] = 0.f;
  return z;
}

// ---------------------------------------------------------------- weights cvt
__global__ __launch_bounds__(256) void k_cvt_w(
    const float* __restrict__ Wq, const float* __restrict__ Wk,
    const float* __restrict__ Wv, const float* __restrict__ Wo,
    unsigned short* __restrict__ Wf) {
  int i   = blockIdx.x * 256 + threadIdx.x;
  int idx = i * 4;
  int p   = idx >> 18;
  int rem = idx & 262143;
  int o = rem >> 9, c0 = rem & 511;
  const float* s = p == 0 ? Wq : p == 1 ? Wk : p == 2 ? Wv : Wo;
  f32x4 v = *(const f32x4*)(s + rem);
  u16x4 pk;
  pk[0] = f2bf(v[0]); pk[1] = f2bf(v[1]); pk[2] = f2bf(v[2]); pk[3] = f2bf(v[3]);
  int mt = o >> 6, fr = (o & 63) >> 4, lr = o & 15;
  int ks = c0 >> 5, lg = (c0 & 31) >> 3, j0 = c0 & 7;  // j0 in {0,4}
  size_t off = (size_t)((((p * 8 + mt) * 16 + ks) * 4 + fr)) * 512 +
               (lg * 16 + lr) * 8 + j0;
  *(u16x4*)(Wf + off) = pk;
}

// ------------------------------------------------------- pack X fragments
__global__ __launch_bounds__(256) void k_pack_xt(
    const float* __restrict__ f0, const float* __restrict__ f1,
    const float* __restrict__ f2, unsigned short* __restrict__ Xf) {
  const int nt = blockIdx.x;            // 0..8  (n tile of 64)
  const int ct = blockIdx.y;            // 0..7  (c tile of 64)
  const int z  = blockIdx.z;            // b*3+f
  const int b = z / 3, f = z % 3;
  const int t = threadIdx.x;
  const float* src = (f == 0 ? f0 : f == 1 ? f1 : f2) + b * (512 * 576);

  __shared__ unsigned short tile[64][65];
#pragma unroll
  for (int i = 0; i < 16; ++i) {
    int idx = i * 256 + t;
    int cc = idx >> 6, nn = idx & 63;    // coalesced over nn
    tile[cc][nn] = f2bf(src[(ct * 64 + cc) * 576 + nt * 64 + nn]);
  }
  __syncthreads();
  const int ntw = f * 9 + nt;            // global m-tile (0..26)
#pragma unroll
  for (int i = 0; i < 4; ++i) {
    int slot = i * 256 + t;              // 1024 slots: [nn=64][cquad=16]
    int nn = slot >> 4, cq = slot & 15;
    int cl = cq * 4;                     // c_local
    int c  = ct * 64 + cl;
    int fc = nn >> 4, lr = nn & 15;
    int ks = c >> 5, lg = (c & 31) >> 3, j0 = c & 7;
    u16x4 pk;
    pk[0] = tile[cl][nn]; pk[1] = tile[cl + 1][nn];
    pk[2] = tile[cl + 2][nn]; pk[3] = tile[cl + 3][nn];
    size_t off = (size_t)((((b * 27 + ntw) * 16 + ks) * 4 + fc)) * 512 +
                 (lg * 16 + lr) * 8 + j0;
    *(u16x4*)(Xf + off) = pk;
  }
}

// ---------------------------------------------------------------- QKV GEMM
// Flat 648-block grid, XCD-remapped: xcd=id&7 -> b=xcd>>1, bx parity=xcd&1.
__global__ __launch_bounds__(256) void k_gemm_qkv(
    const unsigned short* __restrict__ Wf, const unsigned short* __restrict__ Xf,
    const float* __restrict__ bq, const float* __restrict__ bk,
    const float* __restrict__ bv,
    unsigned short* __restrict__ Qf, unsigned short* __restrict__ Kf,
    unsigned short* __restrict__ Vf) {
  const int id = blockIdx.x;                 // 0..647
  const int xcd = id & 7, s = id >> 3;       // s: 0..80
  const int b = xcd >> 1, par = xcd & 1;
  const int p = s / 27, bx = (s % 27) * 2 + par;   // bx: 0..53
  const int t = threadIdx.x, w = t >> 6, l = t & 63, lg = l >> 4, lr = l & 15;
  const int wid = bx * 4 + w;                // 0..215 = 8 mtiles * 27 ntiles
  const int mt = wid / 27, ntw = wid % 27;
  const unsigned short* A = Wf + (size_t)(p * 8 + mt) * 16 * 2048 + l * 8;
  const unsigned short* B = Xf + (size_t)(b * 27 + ntw) * 16 * 2048 + l * 8;

  f32x4 acc[4][4];
#pragma unroll
  for (int fr = 0; fr < 4; ++fr)
#pragma unroll
    for (int fc = 0; fc < 4; ++fc) acc[fr][fc] = (f32x4){0.f, 0.f, 0.f, 0.f};

#pragma unroll 2
  for (int ks = 0; ks < 16; ++ks) {
    bf16x8 af[4], bfv[4];
#pragma unroll
    for (int fr = 0; fr < 4; ++fr)
      af[fr] = *(const bf16x8*)(A + ks * 2048 + fr * 512);
#pragma unroll
    for (int fc = 0; fc < 4; ++fc)
      bfv[fc] = *(const bf16x8*)(B + ks * 2048 + fc * 512);
#pragma unroll
    for (int fr = 0; fr < 4; ++fr)
#pragma unroll
      for (int fc = 0; fc < 4; ++fc)
        acc[fr][fc] = MFMA16(af[fr], bfv[fc], acc[fr][fc]);
  }

  const float* bias = p == 0 ? bq : p == 1 ? bk : bv;
  const int bh = b * 8 + mt;
#pragma unroll
  for (int fr = 0; fr < 4; ++fr) {
    f32x4 b4 = *(const f32x4*)(bias + mt * 64 + fr * 16 + lg * 4);
#pragma unroll
    for (int fc = 0; fc < 4; ++fc) {
      int ck = ntw * 2 + (fc >> 1);
      if (p < 2) {
        unsigned short* outF = (p == 0) ? Qf : Kf;
        u16x4 pk;
#pragma unroll
        for (int r = 0; r < 4; ++r) pk[r] = f2bf(acc[fr][fc][r] + b4[r]);
        size_t off = ((size_t)bh * 54 + ck) * 2048 + fr * 512 +
                     ((lg >> 1) * 32 + (fc & 1) * 16 + lr) * 8 + (lg & 1) * 4;
        *(u16x4*)(outF + off) = pk;
      } else {
        // V identity layout: d=fr*16+lg*4+r -> dt=fr>>1, dlane=(fr&1)*16+lg*4+r;
        //    m=ntw*64+fc*16+lr -> kf2=fc&1, hi=(lr>>3)&1, j=lr&7
        size_t base = ((size_t)bh * 54 + ck) * 2048 +
                      ((fr >> 1) * 2 + (fc & 1)) * 512 +
                      (((lr >> 3) & 1) * 32 + (fr & 1) * 16 + lg * 4) * 8 +
                      (lr & 7);
#pragma unroll
        for (int r = 0; r < 4; ++r)
          Vf[base + r * 8] = f2bf(acc[fr][fc][r] + b4[r]);
      }
    }
  }
}

// ---------------------------------------------------------------- attention
// Block = (g, h, b) via XCD-swizzled 1-D grid: XCD k = id&7 owns bh in
// {4k..4k+3} (per-XCD K/V = 1.8MB, L2-resident). 2 q-tiles per block; 4 waves
// split the 54 KV chunks. Swapped QK^T (mfma32), P in registers via cvt_pk +
// shfl_xor(32) (verified round-3 path). LDS combine epilogue, 2 passes.
__device__ __forceinline__ void attn_tile(const f32x16& s, float& lsum,
                                          f32x16 oacc[2],
                                          const bf16x8 vbf[2][2], int hi) {
  float pv[16];
  float a0 = 0.f, a1 = 0.f;
#pragma unroll
  for (int r = 0; r < 16; ++r) {
    pv[r] = __expf(s[r] * 0.125f);
    if (r & 1) a1 += pv[r]; else a0 += pv[r];
  }
  lsum += a0 + a1;
  unsigned int W[8];
#pragma unroll
  for (int u = 0; u < 8; ++u)
    asm("v_cvt_pk_bf16_f32 %0, %1, %2"
        : "=v"(W[u]) : "v"(pv[2 * u]), "v"(pv[2 * u + 1]));
  unsigned int fw[2][4];
#pragma unroll
  for (int kf = 0; kf < 2; ++kf)
#pragma unroll
    for (int wd = 0; wd < 2; ++wd) {
      unsigned int lo  = W[4 * kf + wd];
      unsigned int hw  = W[4 * kf + 2 + wd];
      unsigned int pub = hi ? lo : hw;
      unsigned int rcv = (unsigned int)__shfl_xor((int)pub, 32, 64);
      fw[kf][wd]     = hi ? rcv : lo;
      fw[kf][2 + wd] = hi ? hw : rcv;
    }
#pragma unroll
  for (int kf2 = 0; kf2 < 2; ++kf2) {
    u32x4 fv;
    fv[0] = fw[kf2][0]; fv[1] = fw[kf2][1];
    fv[2] = fw[kf2][2]; fv[3] = fw[kf2][3];
    bf16x8 pa = __builtin_bit_cast(bf16x8, fv);
#pragma unroll
    for (int dt = 0; dt < 2; ++dt)
      oacc[dt] = MFMA32(pa, vbf[dt][kf2], oacc[dt]);
  }
}

__global__ __launch_bounds__(256) void k_attn(
    const unsigned short* __restrict__ Qf, const unsigned short* __restrict__ Kf,
    const unsigned short* __restrict__ Vf, unsigned short* __restrict__ Of) {
  const int id = blockIdx.x;                 // 0..863
  const int xcd = id & 7, slot = id >> 3;    // slot 0..107
  const int bh = xcd * 4 + (slot / 27);      // XCD k owns bh 4k..4k+3
  const int g  = slot % 27;
  const int b = bh >> 3, h = bh & 7;
  const int t = threadIdx.x, w = t >> 6, l = t & 63;
  const int lr = l & 31, hi = l >> 5;
  const int t0 = g * 2, t1 = g * 2 + 1;

  __shared__ float Obuf[4][32][68];
  __shared__ float Lbuf[4][2][32];

  const unsigned short* Qb0 = Qf + ((size_t)bh * 54 + t0) * 2048 + l * 8;
  const unsigned short* Qb1 = Qf + ((size_t)bh * 54 + t1) * 2048 + l * 8;
  bf16x8 bq0[4], bq1[4];
#pragma unroll
  for (int kf = 0; kf < 4; ++kf) {
    bq0[kf] = *(const bf16x8*)(Qb0 + kf * 512);
    bq1[kf] = *(const bf16x8*)(Qb1 + kf * 512);
  }

  f32x16 o0acc[2], o1acc[2];
  o0acc[0] = zero16(); o0acc[1] = zero16();
  o1acc[0] = zero16(); o1acc[1] = zero16();
  float ls0 = 0.f, ls1 = 0.f;

  const unsigned short* Kb = Kf + (size_t)bh * 54 * 2048 + l * 8;
  const unsigned short* Vb = Vf + (size_t)bh * 54 * 2048 + l * 8;

  for (int ck = w; ck < 54; ck += 4) {
    const unsigned short* kc = Kb + ck * 2048;
    const unsigned short* vc = Vb + ck * 2048;
    bf16x8 ak[4];
#pragma unroll
    for (int kf = 0; kf < 4; ++kf) ak[kf] = *(const bf16x8*)(kc + kf * 512);
    bf16x8 vbf[2][2];
#pragma unroll
    for (int dt = 0; dt < 2; ++dt)
#pragma unroll
      for (int kf2 = 0; kf2 < 2; ++kf2)
        vbf[dt][kf2] = *(const bf16x8*)(vc + (dt * 2 + kf2) * 512);

    f32x16 s0 = zero16();
#pragma unroll
    for (int kf = 0; kf < 4; ++kf) s0 = MFMA32(ak[kf], bq0[kf], s0);
    attn_tile(s0, ls0, o0acc, vbf, hi);

    f32x16 s1 = zero16();
#pragma unroll
    for (int kf = 0; kf < 4; ++kf) s1 = MFMA32(ak[kf], bq1[kf], s1);
    attn_tile(s1, ls1, o1acc, vbf, hi);
  }

  // ---- epilogue: two passes through shared combine buffers
  float lt0 = ls0 + __shfl_xor(ls0, 32, 64);
  float lt1 = ls1 + __shfl_xor(ls1, 32, 64);
  if (l < 32) { Lbuf[w][0][lr] = lt0; Lbuf[w][1][lr] = lt1; }
#pragma unroll
  for (int dt = 0; dt < 2; ++dt)
#pragma unroll
    for (int r = 0; r < 16; ++r)
      Obuf[w][(r & 3) + 8 * (r >> 2) + 4 * hi][dt * 32 + lr] = o0acc[dt][r];
  __syncthreads();

  const int n = t >> 3, d0 = (t & 7) * 8;
  {
    float lt = Lbuf[0][0][n] + Lbuf[1][0][n] + Lbuf[2][0][n] + Lbuf[3][0][n];
    float linv = 1.0f / lt;
    u16x8 o8;
#pragma unroll
    for (int i = 0; i < 8; ++i) {
      float ov = Obuf[0][n][d0 + i] + Obuf[1][n][d0 + i] +
                 Obuf[2][n][d0 + i] + Obuf[3][n][d0 + i];
      o8[i] = f2bf(ov * linv);
    }
    size_t off = (size_t)((((b * 27 + (t0 >> 1)) * 16 + h * 2 + (d0 >> 5)) * 4 +
                           (t0 & 1) * 2 + (n >> 4))) * 512 +
                 ((d0 >> 3) & 3) * 128 + (n & 15) * 8;
    *(u16x8*)(Of + off) = o8;
  }
  __syncthreads();
#pragma unroll
  for (int dt = 0; dt < 2; ++dt)
#pragma unroll
    for (int r = 0; r < 16; ++r)
      Obuf[w][(r & 3) + 8 * (r >> 2) + 4 * hi][dt * 32 + lr] = o1acc[dt][r];
  __syncthreads();
  {
    float lt = Lbuf[0][1][n] + Lbuf[1][1][n] + Lbuf[2][1][n] + Lbuf[3][1][n];
    float linv = 1.0f / lt;
    u16x8 o8;
#pragma unroll
    for (int i = 0; i < 8; ++i) {
      float ov = Obuf[0][n][d0 + i] + Obuf[1][n][d0 + i] +
                 Obuf[2][n][d0 + i] + Obuf[3][n][d0 + i];
      o8[i] = f2bf(ov * linv);
    }
    size_t off = (size_t)((((b * 27 + (t1 >> 1)) * 16 + h * 2 + (d0 >> 5)) * 4 +
                           (t1 & 1) * 2 + (n >> 4))) * 512 +
                 ((d0 >> 3) & 3) * 128 + (n & 15) * 8;
    *(u16x8*)(Of + off) = o8;
  }
}

// ---------------------------------------------------------------- out proj
__global__ __launch_bounds__(256) void k_gemm_out(
    const unsigned short* __restrict__ Wf, const unsigned short* __restrict__ Of,
    const float* __restrict__ bo,
    const float* __restrict__ f0, const float* __restrict__ f1,
    const float* __restrict__ f2, float* __restrict__ out) {
  const int z = blockIdx.z, b = z / 3, f = z % 3;
  const int t = threadIdx.x, w = t >> 6, l = t & 63, lg = l >> 4, lr = l & 15;
  const int wid = blockIdx.x * 4 + w;        // 0..71 = 8 mtiles * 9 ntiles
  const int mt = wid / 9, ntw = wid % 9;
  const int o0 = mt * 64;
  const unsigned short* A = Wf + (size_t)(3 * 8 + mt) * 16 * 2048 + l * 8;
  const unsigned short* B = Of + (size_t)(b * 27 + f * 9 + ntw) * 16 * 2048 + l * 8;

  f32x4 acc[4][4];
#pragma unroll
  for (int fr = 0; fr < 4; ++fr)
#pragma unroll
    for (int fc = 0; fc < 4; ++fc) acc[fr][fc] = (f32x4){0.f, 0.f, 0.f, 0.f};

#pragma unroll 2
  for (int ks = 0; ks < 16; ++ks) {
    bf16x8 af[4], bfv[4];
#pragma unroll
    for (int fr = 0; fr < 4; ++fr)
      af[fr] = *(const bf16x8*)(A + ks * 2048 + fr * 512);
#pragma unroll
    for (int fc = 0; fc < 4; ++fc)
      bfv[fc] = *(const bf16x8*)(B + ks * 2048 + fc * 512);
#pragma unroll
    for (int fr = 0; fr < 4; ++fr)
#pragma unroll
      for (int fc = 0; fc < 4; ++fc)
        acc[fr][fc] = MFMA16(af[fr], bfv[fc], acc[fr][fc]);
  }

  const float* ft = f == 0 ? f0 : f == 1 ? f1 : f2;
#pragma unroll
  for (int fr = 0; fr < 4; ++fr) {
    f32x4 b4 = *(const f32x4*)(bo + o0 + fr * 16 + lg * 4);
#pragma unroll
    for (int fc = 0; fc < 4; ++fc) {
      int ncol = ntw * 64 + fc * 16 + lr;
#pragma unroll
      for (int r = 0; r < 4; ++r) {
        int o = o0 + fr * 16 + lg * 4 + r;
        out[((f * 4 + b) * 512 + o) * 576 + ncol] =
            acc[fr][fc][r] + b4[r] + ft[(b * 512 + o) * 576 + ncol];
      }
    }
  }
}

// ---------------------------------------------------------------- launcher
extern "C" void kernel_launch(void* const* d_in, const int* in_sizes, int n_in,
                              void* d_out, int out_size, void* d_ws, size_t ws_size,
                              hipStream_t stream) {
  const float* f0 = (const float*)d_in[0];
  const float* f1 = (const float*)d_in[1];
  const float* f2 = (const float*)d_in[2];
  const float* Wq = (const float*)d_in[3];
  const float* bq = (const float*)d_in[4];
  const float* Wk = (const float*)d_in[5];
  const float* bk = (const float*)d_in[6];
  const float* Wv = (const float*)d_in[7];
  const float* bv = (const float*)d_in[8];
  const float* Wo = (const float*)d_in[9];
  const float* bo = (const float*)d_in[10];
  float* out = (float*)d_out;

  char* ws = (char*)d_ws;
  unsigned short* Wf = (unsigned short*)(ws);
  unsigned short* Xf = (unsigned short*)(ws + 2097152);
  unsigned short* Qf = (unsigned short*)(ws + 9175040);
  unsigned short* Kf = (unsigned short*)(ws + 16252928);
  unsigned short* Vf = (unsigned short*)(ws + 23330816);
  unsigned short* Of = Xf;  // Xf dead after k_gemm_qkv; reused for attention out

  k_cvt_w<<<1024, 256, 0, stream>>>(Wq, Wk, Wv, Wo, Wf);
  k_pack_xt<<<dim3(9, 8, 12), 256, 0, stream>>>(f0, f1, f2, Xf);
  k_gemm_qkv<<<dim3(648), 256, 0, stream>>>(Wf, Xf, bq, bk, bv, Qf, Kf, Vf);
  k_attn<<<dim3(864), 256, 0, stream>>>(Qf, Kf, Vf, Of);
  k_gemm_out<<<dim3(18, 1, 12), 256, 0, stream>>>(Wf, Of, bo, f0, f1, f2, out);
}

// Round 6
// 108.024 us; speedup vs baseline: 1.8373x; 1.0035x over previous
//
#include <hip/hip_runtime.h>

// ManifoldCrossAttention on MI355X (gfx950), bf16 MFMA pipeline, f32 I/O.
//
// Round 6 = round 5 (verified) + latency-hiding only, no layout changes:
//   k_attn:     next-chunk K fragments prefetched into registers (K is the
//               exposed operand; V latency hides under QK+softmax compute).
//   k_gemm_*:   ping-pong register double-buffer across the 16 K-steps.
// Grids/layouts/epilogues identical to round 5.
//
// Fragment layouts (bf16 element offsets):
//  Wf [p][mt=8][ks=16][fr=4][lane=64][8]   : W[o=mt*64+fr*16+(l&15)][c=ks*32+(l>>4)*8+j]
//  Xf [b][ntw=27][ks=16][fc=4][lane][8]    : X[m=ntw*64+fc*16+(l&15)][c=ks*32+(l>>4)*8+j]
//  Qf/Kf [bh=32][ck=54][kf=4][lane][8]     : M[row=ck*32+(l&31)][d=kf*16+(l>>5)*8+j]
//  Vf [bh][ck=54][dt=2][kf2=2][lane][8]    : V[d=dt*32+(l&31)][m=ck*32+kf2*16+(l>>5)*8+j]
//  Of -- same as Xf (consumed by k_gemm_out as B operand)
//
// Workspace: Wf@0 (2MB), Xf/Of@2097152 (7MB), Qf@9175040, Kf@16252928,
//            Vf@23330816 -- total 30408704 B.

using bf16x8 = __attribute__((ext_vector_type(8))) short;
using f32x4  = __attribute__((ext_vector_type(4))) float;
using f32x16 = __attribute__((ext_vector_type(16))) float;
using u32x4  = __attribute__((ext_vector_type(4))) unsigned int;
using u16x4  = __attribute__((ext_vector_type(4))) unsigned short;
using u16x8  = __attribute__((ext_vector_type(8))) unsigned short;

#define MFMA16(a, b, c) __builtin_amdgcn_mfma_f32_16x16x32_bf16((a), (b), (c), 0, 0, 0)
#define MFMA32(a, b, c) __builtin_amdgcn_mfma_f32_32x32x16_bf16((a), (b), (c), 0, 0, 0)

__device__ __forceinline__ unsigned short f2bf(float f) {
  unsigned int u = __float_as_uint(f);
  return (unsigned short)((u + 0x7fffu + ((u >> 16) & 1u)) >> 16);  // RNE
}

__device__ __forceinline__ f32x16 zero16() {
  f32x16 z;
#pragma unroll
  for (int i = 0; i < 16; ++i) z[i] = 0.f;
  return z;
}

// ---------------------------------------------------------------- weights cvt
__global__ __launch_bounds__(256) void k_cvt_w(
    const float* __restrict__ Wq, const float* __restrict__ Wk,
    const float* __restrict__ Wv, const float* __restrict__ Wo,
    unsigned short* __restrict__ Wf) {
  int i   = blockIdx.x * 256 + threadIdx.x;
  int idx = i * 4;
  int p   = idx >> 18;
  int rem = idx & 262143;
  int o = rem >> 9, c0 = rem & 511;
  const float* s = p == 0 ? Wq : p == 1 ? Wk : p == 2 ? Wv : Wo;
  f32x4 v = *(const f32x4*)(s + rem);
  u16x4 pk;
  pk[0] = f2bf(v[0]); pk[1] = f2bf(v[1]); pk[2] = f2bf(v[2]); pk[3] = f2bf(v[3]);
  int mt = o >> 6, fr = (o & 63) >> 4, lr = o & 15;
  int ks = c0 >> 5, lg = (c0 & 31) >> 3, j0 = c0 & 7;  // j0 in {0,4}
  size_t off = (size_t)((((p * 8 + mt) * 16 + ks) * 4 + fr)) * 512 +
               (lg * 16 + lr) * 8 + j0;
  *(u16x4*)(Wf + off) = pk;
}

// ------------------------------------------------------- pack X fragments
__global__ __launch_bounds__(256) void k_pack_xt(
    const float* __restrict__ f0, const float* __restrict__ f1,
    const float* __restrict__ f2, unsigned short* __restrict__ Xf) {
  const int nt = blockIdx.x;            // 0..8  (n tile of 64)
  const int ct = blockIdx.y;            // 0..7  (c tile of 64)
  const int z  = blockIdx.z;            // b*3+f
  const int b = z / 3, f = z % 3;
  const int t = threadIdx.x;
  const float* src = (f == 0 ? f0 : f == 1 ? f1 : f2) + b * (512 * 576);

  __shared__ unsigned short tile[64][65];
#pragma unroll
  for (int i = 0; i < 16; ++i) {
    int idx = i * 256 + t;
    int cc = idx >> 6, nn = idx & 63;    // coalesced over nn
    tile[cc][nn] = f2bf(src[(ct * 64 + cc) * 576 + nt * 64 + nn]);
  }
  __syncthreads();
  const int ntw = f * 9 + nt;            // global m-tile (0..26)
#pragma unroll
  for (int i = 0; i < 4; ++i) {
    int slot = i * 256 + t;              // 1024 slots: [nn=64][cquad=16]
    int nn = slot >> 4, cq = slot & 15;
    int cl = cq * 4;                     // c_local
    int c  = ct * 64 + cl;
    int fc = nn >> 4, lr = nn & 15;
    int ks = c >> 5, lg = (c & 31) >> 3, j0 = c & 7;
    u16x4 pk;
    pk[0] = tile[cl][nn]; pk[1] = tile[cl + 1][nn];
    pk[2] = tile[cl + 2][nn]; pk[3] = tile[cl + 3][nn];
    size_t off = (size_t)((((b * 27 + ntw) * 16 + ks) * 4 + fc)) * 512 +
                 (lg * 16 + lr) * 8 + j0;
    *(u16x4*)(Xf + off) = pk;
  }
}

// ---------------------------------------------------------------- QKV GEMM
// Flat 648-block grid, XCD-remapped: xcd=id&7 -> b=xcd>>1, bx parity=xcd&1.
// K-loop ping-pong double-buffered (16 steps, even -> no tail copies).
__global__ __launch_bounds__(256) void k_gemm_qkv(
    const unsigned short* __restrict__ Wf, const unsigned short* __restrict__ Xf,
    const float* __restrict__ bq, const float* __restrict__ bk,
    const float* __restrict__ bv,
    unsigned short* __restrict__ Qf, unsigned short* __restrict__ Kf,
    unsigned short* __restrict__ Vf) {
  const int id = blockIdx.x;                 // 0..647
  const int xcd = id & 7, s = id >> 3;       // s: 0..80
  const int b = xcd >> 1, par = xcd & 1;
  const int p = s / 27, bx = (s % 27) * 2 + par;   // bx: 0..53
  const int t = threadIdx.x, w = t >> 6, l = t & 63, lg = l >> 4, lr = l & 15;
  const int wid = bx * 4 + w;                // 0..215 = 8 mtiles * 27 ntiles
  const int mt = wid / 27, ntw = wid % 27;
  const unsigned short* A = Wf + (size_t)(p * 8 + mt) * 16 * 2048 + l * 8;
  const unsigned short* B = Xf + (size_t)(b * 27 + ntw) * 16 * 2048 + l * 8;

  f32x4 acc[4][4];
#pragma unroll
  for (int fr = 0; fr < 4; ++fr)
#pragma unroll
    for (int fc = 0; fc < 4; ++fc) acc[fr][fc] = (f32x4){0.f, 0.f, 0.f, 0.f};

  bf16x8 a0[4], b0[4], a1[4], b1[4];
#pragma unroll
  for (int i = 0; i < 4; ++i) a0[i] = *(const bf16x8*)(A + i * 512);
#pragma unroll
  for (int i = 0; i < 4; ++i) b0[i] = *(const bf16x8*)(B + i * 512);

#pragma unroll 1
  for (int ks = 0; ks < 16; ks += 2) {
    // prefetch ks+1 into buffer 1
#pragma unroll
    for (int i = 0; i < 4; ++i)
      a1[i] = *(const bf16x8*)(A + (ks + 1) * 2048 + i * 512);
#pragma unroll
    for (int i = 0; i < 4; ++i)
      b1[i] = *(const bf16x8*)(B + (ks + 1) * 2048 + i * 512);
    // compute ks on buffer 0
#pragma unroll
    for (int fr = 0; fr < 4; ++fr)
#pragma unroll
      for (int fc = 0; fc < 4; ++fc)
        acc[fr][fc] = MFMA16(a0[fr], b0[fc], acc[fr][fc]);
    // prefetch ks+2 into buffer 0
    if (ks + 2 < 16) {
#pragma unroll
      for (int i = 0; i < 4; ++i)
        a0[i] = *(const bf16x8*)(A + (ks + 2) * 2048 + i * 512);
#pragma unroll
      for (int i = 0; i < 4; ++i)
        b0[i] = *(const bf16x8*)(B + (ks + 2) * 2048 + i * 512);
    }
    // compute ks+1 on buffer 1
#pragma unroll
    for (int fr = 0; fr < 4; ++fr)
#pragma unroll
      for (int fc = 0; fc < 4; ++fc)
        acc[fr][fc] = MFMA16(a1[fr], b1[fc], acc[fr][fc]);
  }

  const float* bias = p == 0 ? bq : p == 1 ? bk : bv;
  const int bh = b * 8 + mt;
#pragma unroll
  for (int fr = 0; fr < 4; ++fr) {
    f32x4 b4 = *(const f32x4*)(bias + mt * 64 + fr * 16 + lg * 4);
#pragma unroll
    for (int fc = 0; fc < 4; ++fc) {
      int ck = ntw * 2 + (fc >> 1);
      if (p < 2) {
        unsigned short* outF = (p == 0) ? Qf : Kf;
        u16x4 pk;
#pragma unroll
        for (int r = 0; r < 4; ++r) pk[r] = f2bf(acc[fr][fc][r] + b4[r]);
        size_t off = ((size_t)bh * 54 + ck) * 2048 + fr * 512 +
                     ((lg >> 1) * 32 + (fc & 1) * 16 + lr) * 8 + (lg & 1) * 4;
        *(u16x4*)(outF + off) = pk;
      } else {
        // V identity layout: d=fr*16+lg*4+r -> dt=fr>>1, dlane=(fr&1)*16+lg*4+r;
        //    m=ntw*64+fc*16+lr -> kf2=fc&1, hi=(lr>>3)&1, j=lr&7
        size_t base = ((size_t)bh * 54 + ck) * 2048 +
                      ((fr >> 1) * 2 + (fc & 1)) * 512 +
                      (((lr >> 3) & 1) * 32 + (fr & 1) * 16 + lg * 4) * 8 +
                      (lr & 7);
#pragma unroll
        for (int r = 0; r < 4; ++r)
          Vf[base + r * 8] = f2bf(acc[fr][fc][r] + b4[r]);
      }
    }
  }
}

// ---------------------------------------------------------------- attention
// Block = (g, h, b) via XCD-swizzled 1-D grid (XCD k owns bh in {4k..4k+3}).
// 2 q-tiles per block; 4 waves split the 54 KV chunks. Swapped QK^T (mfma32),
// P in registers via cvt_pk + shfl_xor(32). NEW: next chunk's K fragments are
// register-prefetched (QK never waits on memory); V issues at iteration top
// and its latency hides under QK+softmax. LDS combine epilogue, 2 passes.
__device__ __forceinline__ void attn_tile(const f32x16& s, float& lsum,
                                          f32x16 oacc[2],
                                          const bf16x8 vb[4], int hi) {
  float pv[16];
  float a0 = 0.f, a1 = 0.f;
#pragma unroll
  for (int r = 0; r < 16; ++r) {
    pv[r] = __expf(s[r] * 0.125f);
    if (r & 1) a1 += pv[r]; else a0 += pv[r];
  }
  lsum += a0 + a1;
  unsigned int W[8];
#pragma unroll
  for (int u = 0; u < 8; ++u)
    asm("v_cvt_pk_bf16_f32 %0, %1, %2"
        : "=v"(W[u]) : "v"(pv[2 * u]), "v"(pv[2 * u + 1]));
  unsigned int fw[2][4];
#pragma unroll
  for (int kf = 0; kf < 2; ++kf)
#pragma unroll
    for (int wd = 0; wd < 2; ++wd) {
      unsigned int lo  = W[4 * kf + wd];
      unsigned int hw  = W[4 * kf + 2 + wd];
      unsigned int pub = hi ? lo : hw;
      unsigned int rcv = (unsigned int)__shfl_xor((int)pub, 32, 64);
      fw[kf][wd]     = hi ? rcv : lo;
      fw[kf][2 + wd] = hi ? hw : rcv;
    }
#pragma unroll
  for (int kf2 = 0; kf2 < 2; ++kf2) {
    u32x4 fv;
    fv[0] = fw[kf2][0]; fv[1] = fw[kf2][1];
    fv[2] = fw[kf2][2]; fv[3] = fw[kf2][3];
    bf16x8 pa = __builtin_bit_cast(bf16x8, fv);
#pragma unroll
    for (int dt = 0; dt < 2; ++dt)
      oacc[dt] = MFMA32(pa, vb[dt * 2 + kf2], oacc[dt]);
  }
}

__global__ __launch_bounds__(256) void k_attn(
    const unsigned short* __restrict__ Qf, const unsigned short* __restrict__ Kf,
    const unsigned short* __restrict__ Vf, unsigned short* __restrict__ Of) {
  const int id = blockIdx.x;                 // 0..863
  const int xcd = id & 7, slot = id >> 3;    // slot 0..107
  const int bh = xcd * 4 + (slot / 27);      // XCD k owns bh 4k..4k+3
  const int g  = slot % 27;
  const int b = bh >> 3, h = bh & 7;
  const int t = threadIdx.x, w = t >> 6, l = t & 63;
  const int lr = l & 31, hi = l >> 5;
  const int t0 = g * 2, t1 = g * 2 + 1;

  __shared__ float Obuf[4][32][68];
  __shared__ float Lbuf[4][2][32];

  const unsigned short* Qb0 = Qf + ((size_t)bh * 54 + t0) * 2048 + l * 8;
  const unsigned short* Qb1 = Qf + ((size_t)bh * 54 + t1) * 2048 + l * 8;
  bf16x8 bq0[4], bq1[4];
#pragma unroll
  for (int kf = 0; kf < 4; ++kf) {
    bq0[kf] = *(const bf16x8*)(Qb0 + kf * 512);
    bq1[kf] = *(const bf16x8*)(Qb1 + kf * 512);
  }

  f32x16 o0acc[2], o1acc[2];
  o0acc[0] = zero16(); o0acc[1] = zero16();
  o1acc[0] = zero16(); o1acc[1] = zero16();
  float ls0 = 0.f, ls1 = 0.f;

  const unsigned short* Kb = Kf + (size_t)bh * 54 * 2048 + l * 8;
  const unsigned short* Vb = Vf + (size_t)bh * 54 * 2048 + l * 8;

  int ck = w;
  bf16x8 ak[4], akn[4], vb[4];
  {
    const unsigned short* kc = Kb + ck * 2048;
#pragma unroll
    for (int i = 0; i < 4; ++i) ak[i] = *(const bf16x8*)(kc + i * 512);
  }
#pragma unroll 1
  for (;;) {
    // V for current chunk: issued here, consumed ~500cyc later in PV.
    const unsigned short* vc = Vb + ck * 2048;
#pragma unroll
    for (int i = 0; i < 4; ++i) vb[i] = *(const bf16x8*)(vc + i * 512);
    // K prefetch for next chunk.
    const int nk = ck + 4;
    if (nk < 54) {
      const unsigned short* kn = Kb + nk * 2048;
#pragma unroll
      for (int i = 0; i < 4; ++i) akn[i] = *(const bf16x8*)(kn + i * 512);
    }

    f32x16 s0 = zero16();
#pragma unroll
    for (int kf = 0; kf < 4; ++kf) s0 = MFMA32(ak[kf], bq0[kf], s0);
    f32x16 s1 = zero16();
#pragma unroll
    for (int kf = 0; kf < 4; ++kf) s1 = MFMA32(ak[kf], bq1[kf], s1);

    attn_tile(s0, ls0, o0acc, vb, hi);
    attn_tile(s1, ls1, o1acc, vb, hi);

    if (nk >= 54) break;
#pragma unroll
    for (int i = 0; i < 4; ++i) ak[i] = akn[i];
    ck = nk;
  }

  // ---- epilogue: two passes through shared combine buffers
  float lt0 = ls0 + __shfl_xor(ls0, 32, 64);
  float lt1 = ls1 + __shfl_xor(ls1, 32, 64);
  if (l < 32) { Lbuf[w][0][lr] = lt0; Lbuf[w][1][lr] = lt1; }
#pragma unroll
  for (int dt = 0; dt < 2; ++dt)
#pragma unroll
    for (int r = 0; r < 16; ++r)
      Obuf[w][(r & 3) + 8 * (r >> 2) + 4 * hi][dt * 32 + lr] = o0acc[dt][r];
  __syncthreads();

  const int n = t >> 3, d0 = (t & 7) * 8;
  {
    float lt = Lbuf[0][0][n] + Lbuf[1][0][n] + Lbuf[2][0][n] + Lbuf[3][0][n];
    float linv = 1.0f / lt;
    u16x8 o8;
#pragma unroll
    for (int i = 0; i < 8; ++i) {
      float ov = Obuf[0][n][d0 + i] + Obuf[1][n][d0 + i] +
                 Obuf[2][n][d0 + i] + Obuf[3][n][d0 + i];
      o8[i] = f2bf(ov * linv);
    }
    size_t off = (size_t)((((b * 27 + (t0 >> 1)) * 16 + h * 2 + (d0 >> 5)) * 4 +
                           (t0 & 1) * 2 + (n >> 4))) * 512 +
                 ((d0 >> 3) & 3) * 128 + (n & 15) * 8;
    *(u16x8*)(Of + off) = o8;
  }
  __syncthreads();
#pragma unroll
  for (int dt = 0; dt < 2; ++dt)
#pragma unroll
    for (int r = 0; r < 16; ++r)
      Obuf[w][(r & 3) + 8 * (r >> 2) + 4 * hi][dt * 32 + lr] = o1acc[dt][r];
  __syncthreads();
  {
    float lt = Lbuf[0][1][n] + Lbuf[1][1][n] + Lbuf[2][1][n] + Lbuf[3][1][n];
    float linv = 1.0f / lt;
    u16x8 o8;
#pragma unroll
    for (int i = 0; i < 8; ++i) {
      float ov = Obuf[0][n][d0 + i] + Obuf[1][n][d0 + i] +
                 Obuf[2][n][d0 + i] + Obuf[3][n][d0 + i];
      o8[i] = f2bf(ov * linv);
    }
    size_t off = (size_t)((((b * 27 + (t1 >> 1)) * 16 + h * 2 + (d0 >> 5)) * 4 +
                           (t1 & 1) * 2 + (n >> 4))) * 512 +
                 ((d0 >> 3) & 3) * 128 + (n & 15) * 8;
    *(u16x8*)(Of + off) = o8;
  }
}

// ---------------------------------------------------------------- out proj
__global__ __launch_bounds__(256) void k_gemm_out(
    const unsigned short* __restrict__ Wf, const unsigned short* __restrict__ Of,
    const float* __restrict__ bo,
    const float* __restrict__ f0, const float* __restrict__ f1,
    const float* __restrict__ f2, float* __restrict__ out) {
  const int z = blockIdx.z, b = z / 3, f = z % 3;
  const int t = threadIdx.x, w = t >> 6, l = t & 63, lg = l >> 4, lr = l & 15;
  const int wid = blockIdx.x * 4 + w;        // 0..71 = 8 mtiles * 9 ntiles
  const int mt = wid / 9, ntw = wid % 9;
  const int o0 = mt * 64;
  const unsigned short* A = Wf + (size_t)(3 * 8 + mt) * 16 * 2048 + l * 8;
  const unsigned short* B = Of + (size_t)(b * 27 + f * 9 + ntw) * 16 * 2048 + l * 8;

  f32x4 acc[4][4];
#pragma unroll
  for (int fr = 0; fr < 4; ++fr)
#pragma unroll
    for (int fc = 0; fc < 4; ++fc) acc[fr][fc] = (f32x4){0.f, 0.f, 0.f, 0.f};

  bf16x8 a0[4], b0[4], a1[4], b1[4];
#pragma unroll
  for (int i = 0; i < 4; ++i) a0[i] = *(const bf16x8*)(A + i * 512);
#pragma unroll
  for (int i = 0; i < 4; ++i) b0[i] = *(const bf16x8*)(B + i * 512);

#pragma unroll 1
  for (int ks = 0; ks < 16; ks += 2) {
#pragma unroll
    for (int i = 0; i < 4; ++i)
      a1[i] = *(const bf16x8*)(A + (ks + 1) * 2048 + i * 512);
#pragma unroll
    for (int i = 0; i < 4; ++i)
      b1[i] = *(const bf16x8*)(B + (ks + 1) * 2048 + i * 512);
#pragma unroll
    for (int fr = 0; fr < 4; ++fr)
#pragma unroll
      for (int fc = 0; fc < 4; ++fc)
        acc[fr][fc] = MFMA16(a0[fr], b0[fc], acc[fr][fc]);
    if (ks + 2 < 16) {
#pragma unroll
      for (int i = 0; i < 4; ++i)
        a0[i] = *(const bf16x8*)(A + (ks + 2) * 2048 + i * 512);
#pragma unroll
      for (int i = 0; i < 4; ++i)
        b0[i] = *(const bf16x8*)(B + (ks + 2) * 2048 + i * 512);
    }
#pragma unroll
    for (int fr = 0; fr < 4; ++fr)
#pragma unroll
      for (int fc = 0; fc < 4; ++fc)
        acc[fr][fc] = MFMA16(a1[fr], b1[fc], acc[fr][fc]);
  }

  const float* ft = f == 0 ? f0 : f == 1 ? f1 : f2;
#pragma unroll
  for (int fr = 0; fr < 4; ++fr) {
    f32x4 b4 = *(const f32x4*)(bo + o0 + fr * 16 + lg * 4);
#pragma unroll
    for (int fc = 0; fc < 4; ++fc) {
      int ncol = ntw * 64 + fc * 16 + lr;
#pragma unroll
      for (int r = 0; r < 4; ++r) {
        int o = o0 + fr * 16 + lg * 4 + r;
        out[((f * 4 + b) * 512 + o) * 576 + ncol] =
            acc[fr][fc][r] + b4[r] + ft[(b * 512 + o) * 576 + ncol];
      }
    }
  }
}

// ---------------------------------------------------------------- launcher
extern "C" void kernel_launch(void* const* d_in, const int* in_sizes, int n_in,
                              void* d_out, int out_size, void* d_ws, size_t ws_size,
                              hipStream_t stream) {
  const float* f0 = (const float*)d_in[0];
  const float* f1 = (const float*)d_in[1];
  const float* f2 = (const float*)d_in[2];
  const float* Wq = (const float*)d_in[3];
  const float* bq = (const float*)d_in[4];
  const float* Wk = (const float*)d_in[5];
  const float* bk = (const float*)d_in[6];
  const float* Wv = (const float*)d_in[7];
  const float* bv = (const float*)d_in[8];
  const float* Wo = (const float*)d_in[9];
  const float* bo = (const float*)d_in[10];
  float* out = (float*)d_out;

  char* ws = (char*)d_ws;
  unsigned short* Wf = (unsigned short*)(ws);
  unsigned short* Xf = (unsigned short*)(ws + 2097152);
  unsigned short* Qf = (unsigned short*)(ws + 9175040);
  unsigned short* Kf = (unsigned short*)(ws + 16252928);
  unsigned short* Vf = (unsigned short*)(ws + 23330816);
  unsigned short* Of = Xf;  // Xf dead after k_gemm_qkv; reused for attention out

  k_cvt_w<<<1024, 256, 0, stream>>>(Wq, Wk, Wv, Wo, Wf);
  k_pack_xt<<<dim3(9, 8, 12), 256, 0, stream>>>(f0, f1, f2, Xf);
  k_gemm_qkv<<<dim3(648), 256, 0, stream>>>(Wf, Xf, bq, bk, bv, Qf, Kf, Vf);
  k_attn<<<dim3(864), 256, 0, stream>>>(Qf, Kf, Vf, Of);
  k_gemm_out<<<dim3(18, 1, 12), 256, 0, stream>>>(Wf, Of, bo, f0, f1, f2, out);
}

// Round 7
// 101.708 us; speedup vs baseline: 1.9514x; 1.0621x over previous
//
#include <hip/hip_runtime.h>

// ManifoldCrossAttention on MI355X (gfx950), bf16 MFMA pipeline, f32 I/O.
//
// Round 7 = round 5 (verified) with attention changes only:
//   (a) exp through inline-asm v_exp_f32 (exp2 with folded scale) -- __expf
//       was suspected of lowering to libm exp (~20 VALU ops): 4.5x VALU bloat.
//   (b) 1 q-tile per block -> 1728 blocks (occupancy: 6.75/CU launched vs
//       3.375; resident cap is 4 blocks/CU). XCD swizzle kept.
//   (c) round-6 K-prefetch reverted (measured regression).
// GEMMs / pack / cvt byte-identical to round 5.
//
// Fragment layouts (bf16 element offsets):
//  Wf [p][mt=8][ks=16][fr=4][lane=64][8]   : W[o=mt*64+fr*16+(l&15)][c=ks*32+(l>>4)*8+j]
//  Xf [b][ntw=27][ks=16][fc=4][lane][8]    : X[m=ntw*64+fc*16+(l&15)][c=ks*32+(l>>4)*8+j]
//  Qf/Kf [bh=32][ck=54][kf=4][lane][8]     : M[row=ck*32+(l&31)][d=kf*16+(l>>5)*8+j]
//  Vf [bh][ck=54][dt=2][kf2=2][lane][8]    : V[d=dt*32+(l&31)][m=ck*32+kf2*16+(l>>5)*8+j]
//  Of -- same as Xf (consumed by k_gemm_out as B operand)
//
// Workspace: Wf@0 (2MB), Xf/Of@2097152 (7MB), Qf@9175040, Kf@16252928,
//            Vf@23330816 -- total 30408704 B.

using bf16x8 = __attribute__((ext_vector_type(8))) short;
using f32x4  = __attribute__((ext_vector_type(4))) float;
using f32x16 = __attribute__((ext_vector_type(16))) float;
using u32x4  = __attribute__((ext_vector_type(4))) unsigned int;
using u16x4  = __attribute__((ext_vector_type(4))) unsigned short;
using u16x8  = __attribute__((ext_vector_type(8))) unsigned short;

#define MFMA16(a, b, c) __builtin_amdgcn_mfma_f32_16x16x32_bf16((a), (b), (c), 0, 0, 0)
#define MFMA32(a, b, c) __builtin_amdgcn_mfma_f32_32x32x16_bf16((a), (b), (c), 0, 0, 0)

__device__ __forceinline__ unsigned short f2bf(float f) {
  unsigned int u = __float_as_uint(f);
  return (unsigned short)((u + 0x7fffu + ((u >> 16) & 1u)) >> 16);  // RNE
}

__device__ __forceinline__ f32x16 zero16() {
  f32x16 z;
#pragma unroll
  for (int i = 0; i < 16; ++i) z[i] = 0.f;
  return z;
}

// ---------------------------------------------------------------- weights cvt
__global__ __launch_bounds__(256) void k_cvt_w(
    const float* __restrict__ Wq, const float* __restrict__ Wk,
    const float* __restrict__ Wv, const float* __restrict__ Wo,
    unsigned short* __restrict__ Wf) {
  int i   = blockIdx.x * 256 + threadIdx.x;
  int idx = i * 4;
  int p   = idx >> 18;
  int rem = idx & 262143;
  int o = rem >> 9, c0 = rem & 511;
  const float* s = p == 0 ? Wq : p == 1 ? Wk : p == 2 ? Wv : Wo;
  f32x4 v = *(const f32x4*)(s + rem);
  u16x4 pk;
  pk[0] = f2bf(v[0]); pk[1] = f2bf(v[1]); pk[2] = f2bf(v[2]); pk[3] = f2bf(v[3]);
  int mt = o >> 6, fr = (o & 63) >> 4, lr = o & 15;
  int ks = c0 >> 5, lg = (c0 & 31) >> 3, j0 = c0 & 7;  // j0 in {0,4}
  size_t off = (size_t)((((p * 8 + mt) * 16 + ks) * 4 + fr)) * 512 +
               (lg * 16 + lr) * 8 + j0;
  *(u16x4*)(Wf + off) = pk;
}

// ------------------------------------------------------- pack X fragments
__global__ __launch_bounds__(256) void k_pack_xt(
    const float* __restrict__ f0, const float* __restrict__ f1,
    const float* __restrict__ f2, unsigned short* __restrict__ Xf) {
  const int nt = blockIdx.x;            // 0..8  (n tile of 64)
  const int ct = blockIdx.y;            // 0..7  (c tile of 64)
  const int z  = blockIdx.z;            // b*3+f
  const int b = z / 3, f = z % 3;
  const int t = threadIdx.x;
  const float* src = (f == 0 ? f0 : f == 1 ? f1 : f2) + b * (512 * 576);

  __shared__ unsigned short tile[64][65];
#pragma unroll
  for (int i = 0; i < 16; ++i) {
    int idx = i * 256 + t;
    int cc = idx >> 6, nn = idx & 63;    // coalesced over nn
    tile[cc][nn] = f2bf(src[(ct * 64 + cc) * 576 + nt * 64 + nn]);
  }
  __syncthreads();
  const int ntw = f * 9 + nt;            // global m-tile (0..26)
#pragma unroll
  for (int i = 0; i < 4; ++i) {
    int slot = i * 256 + t;              // 1024 slots: [nn=64][cquad=16]
    int nn = slot >> 4, cq = slot & 15;
    int cl = cq * 4;                     // c_local
    int c  = ct * 64 + cl;
    int fc = nn >> 4, lr = nn & 15;
    int ks = c >> 5, lg = (c & 31) >> 3, j0 = c & 7;
    u16x4 pk;
    pk[0] = tile[cl][nn]; pk[1] = tile[cl + 1][nn];
    pk[2] = tile[cl + 2][nn]; pk[3] = tile[cl + 3][nn];
    size_t off = (size_t)((((b * 27 + ntw) * 16 + ks) * 4 + fc)) * 512 +
                 (lg * 16 + lr) * 8 + j0;
    *(u16x4*)(Xf + off) = pk;
  }
}

// ---------------------------------------------------------------- QKV GEMM
// Flat 648-block grid, XCD-remapped: xcd=id&7 -> b=xcd>>1, bx parity=xcd&1.
__global__ __launch_bounds__(256) void k_gemm_qkv(
    const unsigned short* __restrict__ Wf, const unsigned short* __restrict__ Xf,
    const float* __restrict__ bq, const float* __restrict__ bk,
    const float* __restrict__ bv,
    unsigned short* __restrict__ Qf, unsigned short* __restrict__ Kf,
    unsigned short* __restrict__ Vf) {
  const int id = blockIdx.x;                 // 0..647
  const int xcd = id & 7, s = id >> 3;       // s: 0..80
  const int b = xcd >> 1, par = xcd & 1;
  const int p = s / 27, bx = (s % 27) * 2 + par;   // bx: 0..53
  const int t = threadIdx.x, w = t >> 6, l = t & 63, lg = l >> 4, lr = l & 15;
  const int wid = bx * 4 + w;                // 0..215 = 8 mtiles * 27 ntiles
  const int mt = wid / 27, ntw = wid % 27;
  const unsigned short* A = Wf + (size_t)(p * 8 + mt) * 16 * 2048 + l * 8;
  const unsigned short* B = Xf + (size_t)(b * 27 + ntw) * 16 * 2048 + l * 8;

  f32x4 acc[4][4];
#pragma unroll
  for (int fr = 0; fr < 4; ++fr)
#pragma unroll
    for (int fc = 0; fc < 4; ++fc) acc[fr][fc] = (f32x4){0.f, 0.f, 0.f, 0.f};

#pragma unroll 2
  for (int ks = 0; ks < 16; ++ks) {
    bf16x8 af[4], bfv[4];
#pragma unroll
    for (int fr = 0; fr < 4; ++fr)
      af[fr] = *(const bf16x8*)(A + ks * 2048 + fr * 512);
#pragma unroll
    for (int fc = 0; fc < 4; ++fc)
      bfv[fc] = *(const bf16x8*)(B + ks * 2048 + fc * 512);
#pragma unroll
    for (int fr = 0; fr < 4; ++fr)
#pragma unroll
      for (int fc = 0; fc < 4; ++fc)
        acc[fr][fc] = MFMA16(af[fr], bfv[fc], acc[fr][fc]);
  }

  const float* bias = p == 0 ? bq : p == 1 ? bk : bv;
  const int bh = b * 8 + mt;
#pragma unroll
  for (int fr = 0; fr < 4; ++fr) {
    f32x4 b4 = *(const f32x4*)(bias + mt * 64 + fr * 16 + lg * 4);
#pragma unroll
    for (int fc = 0; fc < 4; ++fc) {
      int ck = ntw * 2 + (fc >> 1);
      if (p < 2) {
        unsigned short* outF = (p == 0) ? Qf : Kf;
        u16x4 pk;
#pragma unroll
        for (int r = 0; r < 4; ++r) pk[r] = f2bf(acc[fr][fc][r] + b4[r]);
        size_t off = ((size_t)bh * 54 + ck) * 2048 + fr * 512 +
                     ((lg >> 1) * 32 + (fc & 1) * 16 + lr) * 8 + (lg & 1) * 4;
        *(u16x4*)(outF + off) = pk;
      } else {
        // V identity layout: d=fr*16+lg*4+r -> dt=fr>>1, dlane=(fr&1)*16+lg*4+r;
        //    m=ntw*64+fc*16+lr -> kf2=fc&1, hi=(lr>>3)&1, j=lr&7
        size_t base = ((size_t)bh * 54 + ck) * 2048 +
                      ((fr >> 1) * 2 + (fc & 1)) * 512 +
                      (((lr >> 3) & 1) * 32 + (fr & 1) * 16 + lg * 4) * 8 +
                      (lr & 7);
#pragma unroll
        for (int r = 0; r < 4; ++r)
          Vf[base + r * 8] = f2bf(acc[fr][fc][r] + b4[r]);
      }
    }
  }
}

// ---------------------------------------------------------------- attention
// Block = (bh, qt) via XCD-swizzled 1-D grid of 1728: xcd=id&7 owns bh in
// {4k..4k+3}; 1 q-tile (32 rows) per block; 4 waves split the 54 KV chunks.
// Swapped QK^T (mfma32), P in registers via v_exp_f32 + cvt_pk + shfl_xor(32).
// LDS combine epilogue, single pass.
__device__ __forceinline__ void attn_tile(const f32x16& s, float& lsum,
                                          f32x16 oacc[2],
                                          const bf16x8 vb[4], int hi) {
  float pv[16];
  float a0 = 0.f, a1 = 0.f;
#pragma unroll
  for (int r = 0; r < 16; ++r) {
    float e;
    // exp(s/8) == exp2(s * 0.125*log2(e)); single v_mul + v_exp_f32.
    asm("v_exp_f32 %0, %1" : "=v"(e) : "v"(s[r] * 0.18033688f));
    pv[r] = e;
    if (r & 1) a1 += e; else a0 += e;
  }
  lsum += a0 + a1;
  unsigned int W[8];
#pragma unroll
  for (int u = 0; u < 8; ++u)
    asm("v_cvt_pk_bf16_f32 %0, %1, %2"
        : "=v"(W[u]) : "v"(pv[2 * u]), "v"(pv[2 * u + 1]));
  unsigned int fw[2][4];
#pragma unroll
  for (int kf = 0; kf < 2; ++kf)
#pragma unroll
    for (int wd = 0; wd < 2; ++wd) {
      unsigned int lo  = W[4 * kf + wd];
      unsigned int hw  = W[4 * kf + 2 + wd];
      unsigned int pub = hi ? lo : hw;
      unsigned int rcv = (unsigned int)__shfl_xor((int)pub, 32, 64);
      fw[kf][wd]     = hi ? rcv : lo;
      fw[kf][2 + wd] = hi ? hw : rcv;
    }
#pragma unroll
  for (int kf2 = 0; kf2 < 2; ++kf2) {
    u32x4 fv;
    fv[0] = fw[kf2][0]; fv[1] = fw[kf2][1];
    fv[2] = fw[kf2][2]; fv[3] = fw[kf2][3];
    bf16x8 pa = __builtin_bit_cast(bf16x8, fv);
#pragma unroll
    for (int dt = 0; dt < 2; ++dt)
      oacc[dt] = MFMA32(pa, vb[dt * 2 + kf2], oacc[dt]);
  }
}

__global__ __launch_bounds__(256) void k_attn(
    const unsigned short* __restrict__ Qf, const unsigned short* __restrict__ Kf,
    const unsigned short* __restrict__ Vf, unsigned short* __restrict__ Of) {
  const int id = blockIdx.x;                 // 0..1727
  const int xcd = id & 7, slot = id >> 3;    // slot 0..215
  const int bh = xcd * 4 + (slot / 54);      // XCD k owns bh 4k..4k+3
  const int qt = slot % 54;                  // q-tile 0..53
  const int b = bh >> 3, h = bh & 7;
  const int t = threadIdx.x, w = t >> 6, l = t & 63;
  const int lr = l & 31, hi = l >> 5;

  __shared__ float Obuf[4][32][68];
  __shared__ float Lbuf[4][32];

  const unsigned short* Qb = Qf + ((size_t)bh * 54 + qt) * 2048 + l * 8;
  bf16x8 bq[4];
#pragma unroll
  for (int kf = 0; kf < 4; ++kf) bq[kf] = *(const bf16x8*)(Qb + kf * 512);

  f32x16 oacc[2];
  oacc[0] = zero16(); oacc[1] = zero16();
  float ls = 0.f;

  const unsigned short* Kb = Kf + (size_t)bh * 54 * 2048 + l * 8;
  const unsigned short* Vb = Vf + (size_t)bh * 54 * 2048 + l * 8;

  for (int ck = w; ck < 54; ck += 4) {
    const unsigned short* kc = Kb + ck * 2048;
    const unsigned short* vc = Vb + ck * 2048;
    bf16x8 ak[4], vb[4];
#pragma unroll
    for (int kf = 0; kf < 4; ++kf) ak[kf] = *(const bf16x8*)(kc + kf * 512);
#pragma unroll
    for (int i = 0; i < 4; ++i) vb[i] = *(const bf16x8*)(vc + i * 512);

    f32x16 s0 = zero16();
#pragma unroll
    for (int kf = 0; kf < 4; ++kf) s0 = MFMA32(ak[kf], bq[kf], s0);
    attn_tile(s0, ls, oacc, vb, hi);
  }

  // ---- epilogue: combine 4 waves via LDS, normalize, store Of
  float lt = ls + __shfl_xor(ls, 32, 64);
  if (l < 32) Lbuf[w][lr] = lt;
#pragma unroll
  for (int dt = 0; dt < 2; ++dt)
#pragma unroll
    for (int r = 0; r < 16; ++r)
      Obuf[w][(r & 3) + 8 * (r >> 2) + 4 * hi][dt * 32 + lr] = oacc[dt][r];
  __syncthreads();

  const int n = t >> 3, d0 = (t & 7) * 8;
  float ltot = Lbuf[0][n] + Lbuf[1][n] + Lbuf[2][n] + Lbuf[3][n];
  float linv = 1.0f / ltot;
  u16x8 o8;
#pragma unroll
  for (int i = 0; i < 8; ++i) {
    float ov = Obuf[0][n][d0 + i] + Obuf[1][n][d0 + i] +
               Obuf[2][n][d0 + i] + Obuf[3][n][d0 + i];
    o8[i] = f2bf(ov * linv);
  }
  size_t off = (size_t)((((b * 27 + (qt >> 1)) * 16 + h * 2 + (d0 >> 5)) * 4 +
                         (qt & 1) * 2 + (n >> 4))) * 512 +
               ((d0 >> 3) & 3) * 128 + (n & 15) * 8;
  *(u16x8*)(Of + off) = o8;
}

// ---------------------------------------------------------------- out proj
__global__ __launch_bounds__(256) void k_gemm_out(
    const unsigned short* __restrict__ Wf, const unsigned short* __restrict__ Of,
    const float* __restrict__ bo,
    const float* __restrict__ f0, const float* __restrict__ f1,
    const float* __restrict__ f2, float* __restrict__ out) {
  const int z = blockIdx.z, b = z / 3, f = z % 3;
  const int t = threadIdx.x, w = t >> 6, l = t & 63, lg = l >> 4, lr = l & 15;
  const int wid = blockIdx.x * 4 + w;        // 0..71 = 8 mtiles * 9 ntiles
  const int mt = wid / 9, ntw = wid % 9;
  const int o0 = mt * 64;
  const unsigned short* A = Wf + (size_t)(3 * 8 + mt) * 16 * 2048 + l * 8;
  const unsigned short* B = Of + (size_t)(b * 27 + f * 9 + ntw) * 16 * 2048 + l * 8;

  f32x4 acc[4][4];
#pragma unroll
  for (int fr = 0; fr < 4; ++fr)
#pragma unroll
    for (int fc = 0; fc < 4; ++fc) acc[fr][fc] = (f32x4){0.f, 0.f, 0.f, 0.f};

#pragma unroll 2
  for (int ks = 0; ks < 16; ++ks) {
    bf16x8 af[4], bfv[4];
#pragma unroll
    for (int fr = 0; fr < 4; ++fr)
      af[fr] = *(const bf16x8*)(A + ks * 2048 + fr * 512);
#pragma unroll
    for (int fc = 0; fc < 4; ++fc)
      bfv[fc] = *(const bf16x8*)(B + ks * 2048 + fc * 512);
#pragma unroll
    for (int fr = 0; fr < 4; ++fr)
#pragma unroll
      for (int fc = 0; fc < 4; ++fc)
        acc[fr][fc] = MFMA16(af[fr], bfv[fc], acc[fr][fc]);
  }

  const float* ft = f == 0 ? f0 : f == 1 ? f1 : f2;
#pragma unroll
  for (int fr = 0; fr < 4; ++fr) {
    f32x4 b4 = *(const f32x4*)(bo + o0 + fr * 16 + lg * 4);
#pragma unroll
    for (int fc = 0; fc < 4; ++fc) {
      int ncol = ntw * 64 + fc * 16 + lr;
#pragma unroll
      for (int r = 0; r < 4; ++r) {
        int o = o0 + fr * 16 + lg * 4 + r;
        out[((f * 4 + b) * 512 + o) * 576 + ncol] =
            acc[fr][fc][r] + b4[r] + ft[(b * 512 + o) * 576 + ncol];
      }
    }
  }
}

// ---------------------------------------------------------------- launcher
extern "C" void kernel_launch(void* const* d_in, const int* in_sizes, int n_in,
                              void* d_out, int out_size, void* d_ws, size_t ws_size,
                              hipStream_t stream) {
  const float* f0 = (const float*)d_in[0];
  const float* f1 = (const float*)d_in[1];
  const float* f2 = (const float*)d_in[2];
  const float* Wq = (const float*)d_in[3];
  const float* bq = (const float*)d_in[4];
  const float* Wk = (const float*)d_in[5];
  const float* bk = (const float*)d_in[6];
  const float* Wv = (const float*)d_in[7];
  const float* bv = (const float*)d_in[8];
  const float* Wo = (const float*)d_in[9];
  const float* bo = (const float*)d_in[10];
  float* out = (float*)d_out;

  char* ws = (char*)d_ws;
  unsigned short* Wf = (unsigned short*)(ws);
  unsigned short* Xf = (unsigned short*)(ws + 2097152);
  unsigned short* Qf = (unsigned short*)(ws + 9175040);
  unsigned short* Kf = (unsigned short*)(ws + 16252928);
  unsigned short* Vf = (unsigned short*)(ws + 23330816);
  unsigned short* Of = Xf;  // Xf dead after k_gemm_qkv; reused for attention out

  k_cvt_w<<<1024, 256, 0, stream>>>(Wq, Wk, Wv, Wo, Wf);
  k_pack_xt<<<dim3(9, 8, 12), 256, 0, stream>>>(f0, f1, f2, Xf);
  k_gemm_qkv<<<dim3(648), 256, 0, stream>>>(Wf, Xf, bq, bk, bv, Qf, Kf, Vf);
  k_attn<<<dim3(1728), 256, 0, stream>>>(Qf, Kf, Vf, Of);
  k_gemm_out<<<dim3(18, 1, 12), 256, 0, stream>>>(Wf, Of, bo, f0, f1, f2, out);
}

// Round 8
// 100.132 us; speedup vs baseline: 1.9821x; 1.0157x over previous
//
#include <hip/hip_runtime.h>

// ManifoldCrossAttention on MI355X (gfx950), bf16 MFMA pipeline, f32 I/O.
//
// Round 8 = round 7 with:
//   (a) k_attn software-pipelined across KV chunks: per iteration the order is
//       {issue loads(i+1); softmax(i) [VALU, covers load latency]; QK(i+1)
//       [MFMA]; PV(i) [MFMA]} -- breaks the ~800-cyc in-order serial chain
//       load->QK->softmax->shfl->PV that made each wave-step latency-bound.
//   (b) k_cvt_w + k_pack_xt merged into one k_prep dispatch (fewer launches).
// GEMMs byte-identical to round 7/5.
//
// Fragment layouts (bf16 element offsets):
//  Wf [p][mt=8][ks=16][fr=4][lane=64][8]   : W[o=mt*64+fr*16+(l&15)][c=ks*32+(l>>4)*8+j]
//  Xf [b][ntw=27][ks=16][fc=4][lane][8]    : X[m=ntw*64+fc*16+(l&15)][c=ks*32+(l>>4)*8+j]
//  Qf/Kf [bh=32][ck=54][kf=4][lane][8]     : M[row=ck*32+(l&31)][d=kf*16+(l>>5)*8+j]
//  Vf [bh][ck=54][dt=2][kf2=2][lane][8]    : V[d=dt*32+(l&31)][m=ck*32+kf2*16+(l>>5)*8+j]
//  Of -- same as Xf (consumed by k_gemm_out as B operand)
//
// Workspace: Wf@0 (2MB), Xf/Of@2097152 (7MB), Qf@9175040, Kf@16252928,
//            Vf@23330816 -- total 30408704 B.

using bf16x8 = __attribute__((ext_vector_type(8))) short;
using f32x4  = __attribute__((ext_vector_type(4))) float;
using f32x16 = __attribute__((ext_vector_type(16))) float;
using u32x4  = __attribute__((ext_vector_type(4))) unsigned int;
using u16x4  = __attribute__((ext_vector_type(4))) unsigned short;
using u16x8  = __attribute__((ext_vector_type(8))) unsigned short;

#define MFMA16(a, b, c) __builtin_amdgcn_mfma_f32_16x16x32_bf16((a), (b), (c), 0, 0, 0)
#define MFMA32(a, b, c) __builtin_amdgcn_mfma_f32_32x32x16_bf16((a), (b), (c), 0, 0, 0)

__device__ __forceinline__ unsigned short f2bf(float f) {
  unsigned int u = __float_as_uint(f);
  return (unsigned short)((u + 0x7fffu + ((u >> 16) & 1u)) >> 16);  // RNE
}

__device__ __forceinline__ f32x16 zero16() {
  f32x16 z;
#pragma unroll
  for (int i = 0; i < 16; ++i) z[i] = 0.f;
  return z;
}

// ------------------------------------------------- prep: weights cvt + X pack
__global__ __launch_bounds__(256) void k_prep(
    const float* __restrict__ Wq, const float* __restrict__ Wk,
    const float* __restrict__ Wv, const float* __restrict__ Wo,
    const float* __restrict__ f0, const float* __restrict__ f1,
    const float* __restrict__ f2,
    unsigned short* __restrict__ Wf, unsigned short* __restrict__ Xf) {
  __shared__ unsigned short tile[64][65];
  const int bid = blockIdx.x;
  const int t = threadIdx.x;
  if (bid < 1024) {
    // ---- weights cvt: f32 [p][o][c] -> Wf fragments
    int idx = (bid * 256 + t) * 4;
    int p   = idx >> 18;
    int rem = idx & 262143;
    int o = rem >> 9, c0 = rem & 511;
    const float* s = p == 0 ? Wq : p == 1 ? Wk : p == 2 ? Wv : Wo;
    f32x4 v = *(const f32x4*)(s + rem);
    u16x4 pk;
    pk[0] = f2bf(v[0]); pk[1] = f2bf(v[1]); pk[2] = f2bf(v[2]); pk[3] = f2bf(v[3]);
    int mt = o >> 6, fr = (o & 63) >> 4, lr = o & 15;
    int ks = c0 >> 5, lg = (c0 & 31) >> 3, j0 = c0 & 7;  // j0 in {0,4}
    size_t off = (size_t)((((p * 8 + mt) * 16 + ks) * 4 + fr)) * 512 +
                 (lg * 16 + lr) * 8 + j0;
    *(u16x4*)(Wf + off) = pk;
    return;
  }
  // ---- X pack (was k_pack_xt): id -> (nt, ct, z)
  const int id = bid - 1024;
  const int nt = id % 9;                // n tile of 64
  const int ct = (id / 9) % 8;          // c tile of 64
  const int z  = id / 72;               // b*3+f
  const int b = z / 3, f = z % 3;
  const float* src = (f == 0 ? f0 : f == 1 ? f1 : f2) + b * (512 * 576);

#pragma unroll
  for (int i = 0; i < 16; ++i) {
    int idx = i * 256 + t;
    int cc = idx >> 6, nn = idx & 63;    // coalesced over nn
    tile[cc][nn] = f2bf(src[(ct * 64 + cc) * 576 + nt * 64 + nn]);
  }
  __syncthreads();
  const int ntw = f * 9 + nt;            // global m-tile (0..26)
#pragma unroll
  for (int i = 0; i < 4; ++i) {
    int slot = i * 256 + t;              // 1024 slots: [nn=64][cquad=16]
    int nn = slot >> 4, cq = slot & 15;
    int cl = cq * 4;                     // c_local
    int c  = ct * 64 + cl;
    int fc = nn >> 4, lr = nn & 15;
    int ks = c >> 5, lg = (c & 31) >> 3, j0 = c & 7;
    u16x4 pk;
    pk[0] = tile[cl][nn]; pk[1] = tile[cl + 1][nn];
    pk[2] = tile[cl + 2][nn]; pk[3] = tile[cl + 3][nn];
    size_t off = (size_t)((((b * 27 + ntw) * 16 + ks) * 4 + fc)) * 512 +
                 (lg * 16 + lr) * 8 + j0;
    *(u16x4*)(Xf + off) = pk;
  }
}

// ---------------------------------------------------------------- QKV GEMM
// Flat 648-block grid, XCD-remapped: xcd=id&7 -> b=xcd>>1, bx parity=xcd&1.
__global__ __launch_bounds__(256) void k_gemm_qkv(
    const unsigned short* __restrict__ Wf, const unsigned short* __restrict__ Xf,
    const float* __restrict__ bq, const float* __restrict__ bk,
    const float* __restrict__ bv,
    unsigned short* __restrict__ Qf, unsigned short* __restrict__ Kf,
    unsigned short* __restrict__ Vf) {
  const int id = blockIdx.x;                 // 0..647
  const int xcd = id & 7, s = id >> 3;       // s: 0..80
  const int b = xcd >> 1, par = xcd & 1;
  const int p = s / 27, bx = (s % 27) * 2 + par;   // bx: 0..53
  const int t = threadIdx.x, w = t >> 6, l = t & 63, lg = l >> 4, lr = l & 15;
  const int wid = bx * 4 + w;                // 0..215 = 8 mtiles * 27 ntiles
  const int mt = wid / 27, ntw = wid % 27;
  const unsigned short* A = Wf + (size_t)(p * 8 + mt) * 16 * 2048 + l * 8;
  const unsigned short* B = Xf + (size_t)(b * 27 + ntw) * 16 * 2048 + l * 8;

  f32x4 acc[4][4];
#pragma unroll
  for (int fr = 0; fr < 4; ++fr)
#pragma unroll
    for (int fc = 0; fc < 4; ++fc) acc[fr][fc] = (f32x4){0.f, 0.f, 0.f, 0.f};

#pragma unroll 2
  for (int ks = 0; ks < 16; ++ks) {
    bf16x8 af[4], bfv[4];
#pragma unroll
    for (int fr = 0; fr < 4; ++fr)
      af[fr] = *(const bf16x8*)(A + ks * 2048 + fr * 512);
#pragma unroll
    for (int fc = 0; fc < 4; ++fc)
      bfv[fc] = *(const bf16x8*)(B + ks * 2048 + fc * 512);
#pragma unroll
    for (int fr = 0; fr < 4; ++fr)
#pragma unroll
      for (int fc = 0; fc < 4; ++fc)
        acc[fr][fc] = MFMA16(af[fr], bfv[fc], acc[fr][fc]);
  }

  const float* bias = p == 0 ? bq : p == 1 ? bk : bv;
  const int bh = b * 8 + mt;
#pragma unroll
  for (int fr = 0; fr < 4; ++fr) {
    f32x4 b4 = *(const f32x4*)(bias + mt * 64 + fr * 16 + lg * 4);
#pragma unroll
    for (int fc = 0; fc < 4; ++fc) {
      int ck = ntw * 2 + (fc >> 1);
      if (p < 2) {
        unsigned short* outF = (p == 0) ? Qf : Kf;
        u16x4 pk;
#pragma unroll
        for (int r = 0; r < 4; ++r) pk[r] = f2bf(acc[fr][fc][r] + b4[r]);
        size_t off = ((size_t)bh * 54 + ck) * 2048 + fr * 512 +
                     ((lg >> 1) * 32 + (fc & 1) * 16 + lr) * 8 + (lg & 1) * 4;
        *(u16x4*)(outF + off) = pk;
      } else {
        // V identity layout: d=fr*16+lg*4+r -> dt=fr>>1, dlane=(fr&1)*16+lg*4+r;
        //    m=ntw*64+fc*16+lr -> kf2=fc&1, hi=(lr>>3)&1, j=lr&7
        size_t base = ((size_t)bh * 54 + ck) * 2048 +
                      ((fr >> 1) * 2 + (fc & 1)) * 512 +
                      (((lr >> 3) & 1) * 32 + (fr & 1) * 16 + lg * 4) * 8 +
                      (lr & 7);
#pragma unroll
        for (int r = 0; r < 4; ++r)
          Vf[base + r * 8] = f2bf(acc[fr][fc][r] + b4[r]);
      }
    }
  }
}

// ---------------------------------------------------------------- attention
// Block = (bh, qt), XCD-swizzled grid of 1728; 4 waves split the 54 KV chunks.
// Software-pipelined: softmax(i) runs before QK(i+1) so VALU covers the K-load
// latency and the MFMA pipe goes QK(i+1) -> PV(i) back-to-back.
__device__ __forceinline__ void softmax_pa(const f32x16& s, float& lsum,
                                           bf16x8& pa0, bf16x8& pa1, int hi) {
  unsigned int W[8];
  float a0 = 0.f, a1 = 0.f;
#pragma unroll
  for (int u = 0; u < 8; ++u) {
    float e0, e1;
    // exp(s/8) == exp2(s * 0.125*log2(e)); single v_mul + v_exp_f32.
    asm("v_exp_f32 %0, %1" : "=v"(e0) : "v"(s[2 * u] * 0.18033688f));
    asm("v_exp_f32 %0, %1" : "=v"(e1) : "v"(s[2 * u + 1] * 0.18033688f));
    a0 += e0; a1 += e1;
    asm("v_cvt_pk_bf16_f32 %0, %1, %2" : "=v"(W[u]) : "v"(e0), "v"(e1));
  }
  lsum += a0 + a1;
  unsigned int fw[2][4];
#pragma unroll
  for (int kf = 0; kf < 2; ++kf)
#pragma unroll
    for (int wd = 0; wd < 2; ++wd) {
      unsigned int lo  = W[4 * kf + wd];
      unsigned int hw  = W[4 * kf + 2 + wd];
      unsigned int pub = hi ? lo : hw;
      unsigned int rcv = (unsigned int)__shfl_xor((int)pub, 32, 64);
      fw[kf][wd]     = hi ? rcv : lo;
      fw[kf][2 + wd] = hi ? hw : rcv;
    }
  u32x4 w0, w1;
  w0[0] = fw[0][0]; w0[1] = fw[0][1]; w0[2] = fw[0][2]; w0[3] = fw[0][3];
  w1[0] = fw[1][0]; w1[1] = fw[1][1]; w1[2] = fw[1][2]; w1[3] = fw[1][3];
  pa0 = __builtin_bit_cast(bf16x8, w0);
  pa1 = __builtin_bit_cast(bf16x8, w1);
}

__global__ __launch_bounds__(256) void k_attn(
    const unsigned short* __restrict__ Qf, const unsigned short* __restrict__ Kf,
    const unsigned short* __restrict__ Vf, unsigned short* __restrict__ Of) {
  const int id = blockIdx.x;                 // 0..1727
  const int xcd = id & 7, slot = id >> 3;    // slot 0..215
  const int bh = xcd * 4 + (slot / 54);      // XCD k owns bh 4k..4k+3
  const int qt = slot % 54;                  // q-tile 0..53
  const int b = bh >> 3, h = bh & 7;
  const int t = threadIdx.x, w = t >> 6, l = t & 63;
  const int lr = l & 31, hi = l >> 5;

  __shared__ float Obuf[4][32][68];
  __shared__ float Lbuf[4][32];

  const unsigned short* Qb = Qf + ((size_t)bh * 54 + qt) * 2048 + l * 8;
  bf16x8 bq[4];
#pragma unroll
  for (int kf = 0; kf < 4; ++kf) bq[kf] = *(const bf16x8*)(Qb + kf * 512);

  f32x16 oacc[2];
  oacc[0] = zero16(); oacc[1] = zero16();
  float ls = 0.f;

  const unsigned short* Kb = Kf + (size_t)bh * 54 * 2048 + l * 8;
  const unsigned short* Vb = Vf + (size_t)bh * 54 * 2048 + l * 8;

  // ---- prologue: chunk w
  bf16x8 ak[4], vb[4];
  {
    const unsigned short* kc = Kb + w * 2048;
    const unsigned short* vc = Vb + w * 2048;
#pragma unroll
    for (int i = 0; i < 4; ++i) ak[i] = *(const bf16x8*)(kc + i * 512);
#pragma unroll
    for (int i = 0; i < 4; ++i) vb[i] = *(const bf16x8*)(vc + i * 512);
  }
  f32x16 sA = zero16();
#pragma unroll
  for (int kf = 0; kf < 4; ++kf) sA = MFMA32(ak[kf], bq[kf], sA);

  // ---- pipelined main loop
#pragma unroll 1
  for (int ck = w + 4; ck < 54; ck += 4) {
    bf16x8 akn[4], vbn[4];
    const unsigned short* kn = Kb + ck * 2048;
    const unsigned short* vn = Vb + ck * 2048;
#pragma unroll
    for (int i = 0; i < 4; ++i) akn[i] = *(const bf16x8*)(kn + i * 512);
#pragma unroll
    for (int i = 0; i < 4; ++i) vbn[i] = *(const bf16x8*)(vn + i * 512);

    bf16x8 pa0, pa1;
    softmax_pa(sA, ls, pa0, pa1, hi);       // VALU: covers akn load latency

    f32x16 sB = zero16();
#pragma unroll
    for (int kf = 0; kf < 4; ++kf) sB = MFMA32(akn[kf], bq[kf], sB);

    oacc[0] = MFMA32(pa0, vb[0], oacc[0]);  // PV(i): vb long resident
    oacc[0] = MFMA32(pa1, vb[1], oacc[0]);
    oacc[1] = MFMA32(pa0, vb[2], oacc[1]);
    oacc[1] = MFMA32(pa1, vb[3], oacc[1]);

    sA = sB;
#pragma unroll
    for (int i = 0; i < 4; ++i) vb[i] = vbn[i];
  }

  // ---- drain last chunk
  {
    bf16x8 pa0, pa1;
    softmax_pa(sA, ls, pa0, pa1, hi);
    oacc[0] = MFMA32(pa0, vb[0], oacc[0]);
    oacc[0] = MFMA32(pa1, vb[1], oacc[0]);
    oacc[1] = MFMA32(pa0, vb[2], oacc[1]);
    oacc[1] = MFMA32(pa1, vb[3], oacc[1]);
  }

  // ---- epilogue: combine 4 waves via LDS, normalize, store Of
  float lt = ls + __shfl_xor(ls, 32, 64);
  if (l < 32) Lbuf[w][lr] = lt;
#pragma unroll
  for (int dt = 0; dt < 2; ++dt)
#pragma unroll
    for (int r = 0; r < 16; ++r)
      Obuf[w][(r & 3) + 8 * (r >> 2) + 4 * hi][dt * 32 + lr] = oacc[dt][r];
  __syncthreads();

  const int n = t >> 3, d0 = (t & 7) * 8;
  float ltot = Lbuf[0][n] + Lbuf[1][n] + Lbuf[2][n] + Lbuf[3][n];
  float linv = 1.0f / ltot;
  u16x8 o8;
#pragma unroll
  for (int i = 0; i < 8; ++i) {
    float ov = Obuf[0][n][d0 + i] + Obuf[1][n][d0 + i] +
               Obuf[2][n][d0 + i] + Obuf[3][n][d0 + i];
    o8[i] = f2bf(ov * linv);
  }
  size_t off = (size_t)((((b * 27 + (qt >> 1)) * 16 + h * 2 + (d0 >> 5)) * 4 +
                         (qt & 1) * 2 + (n >> 4))) * 512 +
               ((d0 >> 3) & 3) * 128 + (n & 15) * 8;
  *(u16x8*)(Of + off) = o8;
}

// ---------------------------------------------------------------- out proj
__global__ __launch_bounds__(256) void k_gemm_out(
    const unsigned short* __restrict__ Wf, const unsigned short* __restrict__ Of,
    const float* __restrict__ bo,
    const float* __restrict__ f0, const float* __restrict__ f1,
    const float* __restrict__ f2, float* __restrict__ out) {
  const int z = blockIdx.z, b = z / 3, f = z % 3;
  const int t = threadIdx.x, w = t >> 6, l = t & 63, lg = l >> 4, lr = l & 15;
  const int wid = blockIdx.x * 4 + w;        // 0..71 = 8 mtiles * 9 ntiles
  const int mt = wid / 9, ntw = wid % 9;
  const int o0 = mt * 64;
  const unsigned short* A = Wf + (size_t)(3 * 8 + mt) * 16 * 2048 + l * 8;
  const unsigned short* B = Of + (size_t)(b * 27 + f * 9 + ntw) * 16 * 2048 + l * 8;

  f32x4 acc[4][4];
#pragma unroll
  for (int fr = 0; fr < 4; ++fr)
#pragma unroll
    for (int fc = 0; fc < 4; ++fc) acc[fr][fc] = (f32x4){0.f, 0.f, 0.f, 0.f};

#pragma unroll 2
  for (int ks = 0; ks < 16; ++ks) {
    bf16x8 af[4], bfv[4];
#pragma unroll
    for (int fr = 0; fr < 4; ++fr)
      af[fr] = *(const bf16x8*)(A + ks * 2048 + fr * 512);
#pragma unroll
    for (int fc = 0; fc < 4; ++fc)
      bfv[fc] = *(const bf16x8*)(B + ks * 2048 + fc * 512);
#pragma unroll
    for (int fr = 0; fr < 4; ++fr)
#pragma unroll
      for (int fc = 0; fc < 4; ++fc)
        acc[fr][fc] = MFMA16(af[fr], bfv[fc], acc[fr][fc]);
  }

  const float* ft = f == 0 ? f0 : f == 1 ? f1 : f2;
#pragma unroll
  for (int fr = 0; fr < 4; ++fr) {
    f32x4 b4 = *(const f32x4*)(bo + o0 + fr * 16 + lg * 4);
#pragma unroll
    for (int fc = 0; fc < 4; ++fc) {
      int ncol = ntw * 64 + fc * 16 + lr;
#pragma unroll
      for (int r = 0; r < 4; ++r) {
        int o = o0 + fr * 16 + lg * 4 + r;
        out[((f * 4 + b) * 512 + o) * 576 + ncol] =
            acc[fr][fc][r] + b4[r] + ft[(b * 512 + o) * 576 + ncol];
      }
    }
  }
}

// ---------------------------------------------------------------- launcher
extern "C" void kernel_launch(void* const* d_in, const int* in_sizes, int n_in,
                              void* d_out, int out_size, void* d_ws, size_t ws_size,
                              hipStream_t stream) {
  const float* f0 = (const float*)d_in[0];
  const float* f1 = (const float*)d_in[1];
  const float* f2 = (const float*)d_in[2];
  const float* Wq = (const float*)d_in[3];
  const float* bq = (const float*)d_in[4];
  const float* Wk = (const float*)d_in[5];
  const float* bk = (const float*)d_in[6];
  const float* Wv = (const float*)d_in[7];
  const float* bv = (const float*)d_in[8];
  const float* Wo = (const float*)d_in[9];
  const float* bo = (const float*)d_in[10];
  float* out = (float*)d_out;

  char* ws = (char*)d_ws;
  unsigned short* Wf = (unsigned short*)(ws);
  unsigned short* Xf = (unsigned short*)(ws + 2097152);
  unsigned short* Qf = (unsigned short*)(ws + 9175040);
  unsigned short* Kf = (unsigned short*)(ws + 16252928);
  unsigned short* Vf = (unsigned short*)(ws + 23330816);
  unsigned short* Of = Xf;  // Xf dead after k_gemm_qkv; reused for attention out

  k_prep<<<dim3(1888), 256, 0, stream>>>(Wq, Wk, Wv, Wo, f0, f1, f2, Wf, Xf);
  k_gemm_qkv<<<dim3(648), 256, 0, stream>>>(Wf, Xf, bq, bk, bv, Qf, Kf, Vf);
  k_attn<<<dim3(1728), 256, 0, stream>>>(Qf, Kf, Vf, Of);
  k_gemm_out<<<dim3(18, 1, 12), 256, 0, stream>>>(Wf, Of, bo, f0, f1, f2, out);
}

// Round 9
// 89.995 us; speedup vs baseline: 2.2053x; 1.1126x over previous
//
#include <hip/hip_runtime.h>

// ManifoldCrossAttention on MI355X (gfx950), bf16 MFMA pipeline, f32 I/O.
//
// Round 9:
//   k_attn: register diet to get under the 128-unified-VGPR occupancy cliff
//     (was ~136 -> 2 waves/SIMD; target <=128 -> 4 waves/SIMD via
//     __launch_bounds__(256,4)): pipeline removed, V loaded after QK (reuses
//     K's registers, latency covered by softmax), softmax scale folded into
//     the Q producer (Qf pre-scaled by 0.125*log2(e) -> v_exp directly).
//   k_gemm_qkv / k_gemm_out: re-tiled 64x64 -> 64x32 per wave (2x waves:
//     5.1/SIMD and 1.7/SIMD launched) for latency hiding; qkv epilogue
//     simplifies (ck = ntw*2+half is per-wave constant).
//
// Fragment layouts (bf16 element offsets):
//  Wf [p][mt=8][ks=16][fr=4][lane=64][8]   : W[o=mt*64+fr*16+(l&15)][c=ks*32+(l>>4)*8+j]
//  Xf [b][ntw=27][ks=16][fc=4][lane][8]    : X[m=ntw*64+fc*16+(l&15)][c=ks*32+(l>>4)*8+j]
//  Qf/Kf [bh=32][ck=54][kf=4][lane][8]     : M[row=ck*32+(l&31)][d=kf*16+(l>>5)*8+j]
//     (Qf values pre-scaled by 0.18033688 = 0.125*log2(e))
//  Vf [bh][ck=54][dt=2][kf2=2][lane][8]    : V[d=dt*32+(l&31)][m=ck*32+kf2*16+(l>>5)*8+j]
//  Of -- same as Xf (consumed by k_gemm_out as B operand)
//
// Workspace: Wf@0 (2MB), Xf/Of@2097152 (7MB), Qf@9175040, Kf@16252928,
//            Vf@23330816 -- total 30408704 B.

using bf16x8 = __attribute__((ext_vector_type(8))) short;
using f32x4  = __attribute__((ext_vector_type(4))) float;
using f32x16 = __attribute__((ext_vector_type(16))) float;
using u32x4  = __attribute__((ext_vector_type(4))) unsigned int;
using u16x4  = __attribute__((ext_vector_type(4))) unsigned short;
using u16x8  = __attribute__((ext_vector_type(8))) unsigned short;

#define MFMA16(a, b, c) __builtin_amdgcn_mfma_f32_16x16x32_bf16((a), (b), (c), 0, 0, 0)
#define MFMA32(a, b, c) __builtin_amdgcn_mfma_f32_32x32x16_bf16((a), (b), (c), 0, 0, 0)

__device__ __forceinline__ unsigned short f2bf(float f) {
  unsigned int u = __float_as_uint(f);
  return (unsigned short)((u + 0x7fffu + ((u >> 16) & 1u)) >> 16);  // RNE
}

__device__ __forceinline__ f32x16 zero16() {
  f32x16 z;
#pragma unroll
  for (int i = 0; i < 16; ++i) z[i] = 0.f;
  return z;
}

// ------------------------------------------------- prep: weights cvt + X pack
__global__ __launch_bounds__(256) void k_prep(
    const float* __restrict__ Wq, const float* __restrict__ Wk,
    const float* __restrict__ Wv, const float* __restrict__ Wo,
    const float* __restrict__ f0, const float* __restrict__ f1,
    const float* __restrict__ f2,
    unsigned short* __restrict__ Wf, unsigned short* __restrict__ Xf) {
  __shared__ unsigned short tile[64][65];
  const int bid = blockIdx.x;
  const int t = threadIdx.x;
  if (bid < 1024) {
    int idx = (bid * 256 + t) * 4;
    int p   = idx >> 18;
    int rem = idx & 262143;
    int o = rem >> 9, c0 = rem & 511;
    const float* s = p == 0 ? Wq : p == 1 ? Wk : p == 2 ? Wv : Wo;
    f32x4 v = *(const f32x4*)(s + rem);
    u16x4 pk;
    pk[0] = f2bf(v[0]); pk[1] = f2bf(v[1]); pk[2] = f2bf(v[2]); pk[3] = f2bf(v[3]);
    int mt = o >> 6, fr = (o & 63) >> 4, lr = o & 15;
    int ks = c0 >> 5, lg = (c0 & 31) >> 3, j0 = c0 & 7;  // j0 in {0,4}
    size_t off = (size_t)((((p * 8 + mt) * 16 + ks) * 4 + fr)) * 512 +
                 (lg * 16 + lr) * 8 + j0;
    *(u16x4*)(Wf + off) = pk;
    return;
  }
  const int id = bid - 1024;
  const int nt = id % 9;                // n tile of 64
  const int ct = (id / 9) % 8;          // c tile of 64
  const int z  = id / 72;               // b*3+f
  const int b = z / 3, f = z % 3;
  const float* src = (f == 0 ? f0 : f == 1 ? f1 : f2) + b * (512 * 576);

#pragma unroll
  for (int i = 0; i < 16; ++i) {
    int idx = i * 256 + t;
    int cc = idx >> 6, nn = idx & 63;    // coalesced over nn
    tile[cc][nn] = f2bf(src[(ct * 64 + cc) * 576 + nt * 64 + nn]);
  }
  __syncthreads();
  const int ntw = f * 9 + nt;            // global m-tile (0..26)
#pragma unroll
  for (int i = 0; i < 4; ++i) {
    int slot = i * 256 + t;              // 1024 slots: [nn=64][cquad=16]
    int nn = slot >> 4, cq = slot & 15;
    int cl = cq * 4;                     // c_local
    int c  = ct * 64 + cl;
    int fc = nn >> 4, lr = nn & 15;
    int ks = c >> 5, lg = (c & 31) >> 3, j0 = c & 7;
    u16x4 pk;
    pk[0] = tile[cl][nn]; pk[1] = tile[cl + 1][nn];
    pk[2] = tile[cl + 2][nn]; pk[3] = tile[cl + 3][nn];
    size_t off = (size_t)((((b * 27 + ntw) * 16 + ks) * 4 + fc)) * 512 +
                 (lg * 16 + lr) * 8 + j0;
    *(u16x4*)(Xf + off) = pk;
  }
}

// ---------------------------------------------------------------- QKV GEMM
// 64x32 tiles per wave, 1296 blocks, XCD-remapped (b = xcd>>1, parity = xcd&1).
__global__ __launch_bounds__(256) void k_gemm_qkv(
    const unsigned short* __restrict__ Wf, const unsigned short* __restrict__ Xf,
    const float* __restrict__ bq, const float* __restrict__ bk,
    const float* __restrict__ bv,
    unsigned short* __restrict__ Qf, unsigned short* __restrict__ Kf,
    unsigned short* __restrict__ Vf) {
  const int id = blockIdx.x;                 // 0..1295
  const int xcd = id & 7, s = id >> 3;       // s: 0..161
  const int b = xcd >> 1, par = xcd & 1;
  const int p = s / 54, bx = (s % 54) * 2 + par;   // bx: 0..107
  const int t = threadIdx.x, w = t >> 6, l = t & 63, lg = l >> 4, lr = l & 15;
  const int wid = bx * 4 + w;                // 0..431 = 8 mt * 27 ntw * 2 half
  const int mt = wid / 54, rest = wid % 54;
  const int ntw = rest >> 1, half = rest & 1;
  const unsigned short* A = Wf + (size_t)(p * 8 + mt) * 16 * 2048 + l * 8;
  const unsigned short* B = Xf + (size_t)(b * 27 + ntw) * 16 * 2048 +
                            half * 1024 + l * 8;

  f32x4 acc[4][2];
#pragma unroll
  for (int fr = 0; fr < 4; ++fr)
#pragma unroll
    for (int fc = 0; fc < 2; ++fc) acc[fr][fc] = (f32x4){0.f, 0.f, 0.f, 0.f};

#pragma unroll 2
  for (int ks = 0; ks < 16; ++ks) {
    bf16x8 af[4], bfv[2];
#pragma unroll
    for (int fr = 0; fr < 4; ++fr)
      af[fr] = *(const bf16x8*)(A + ks * 2048 + fr * 512);
#pragma unroll
    for (int fc = 0; fc < 2; ++fc)
      bfv[fc] = *(const bf16x8*)(B + ks * 2048 + fc * 512);
#pragma unroll
    for (int fr = 0; fr < 4; ++fr)
#pragma unroll
      for (int fc = 0; fc < 2; ++fc)
        acc[fr][fc] = MFMA16(af[fr], bfv[fc], acc[fr][fc]);
  }

  const float* bias = p == 0 ? bq : p == 1 ? bk : bv;
  const int bh = b * 8 + mt;
  const int ck = ntw * 2 + half;             // per-wave constant KV chunk
#pragma unroll
  for (int fr = 0; fr < 4; ++fr) {
    f32x4 b4 = *(const f32x4*)(bias + mt * 64 + fr * 16 + lg * 4);
#pragma unroll
    for (int fc = 0; fc < 2; ++fc) {
      if (p < 2) {
        unsigned short* outF = (p == 0) ? Qf : Kf;
        u16x4 pk;
#pragma unroll
        for (int r = 0; r < 4; ++r) {
          float v = acc[fr][fc][r] + b4[r];
          if (p == 0) v *= 0.18033688f;      // fold softmax scale into Q
          pk[r] = f2bf(v);
        }
        size_t off = ((size_t)bh * 54 + ck) * 2048 + fr * 512 +
                     ((lg >> 1) * 32 + fc * 16 + lr) * 8 + (lg & 1) * 4;
        *(u16x4*)(outF + off) = pk;
      } else {
        size_t base = ((size_t)bh * 54 + ck) * 2048 +
                      ((fr >> 1) * 2 + fc) * 512 +
                      (((lr >> 3) & 1) * 32 + (fr & 1) * 16 + lg * 4) * 8 +
                      (lr & 7);
#pragma unroll
        for (int r = 0; r < 4; ++r)
          Vf[base + r * 8] = f2bf(acc[fr][fc][r] + b4[r]);
      }
    }
  }
}

// ---------------------------------------------------------------- attention
// Block = (bh, qt), XCD-swizzled grid of 1728; 4 waves split the 54 KV chunks.
// Reg-dieted to fit 4 waves/SIMD: no pipeline; V loaded after QK (reuses K's
// registers, latency covered by softmax); Q pre-scaled so exp is bare v_exp.
__global__ __launch_bounds__(256, 4) void k_attn(
    const unsigned short* __restrict__ Qf, const unsigned short* __restrict__ Kf,
    const unsigned short* __restrict__ Vf, unsigned short* __restrict__ Of) {
  const int id = blockIdx.x;                 // 0..1727
  const int xcd = id & 7, slot = id >> 3;    // slot 0..215
  const int bh = xcd * 4 + (slot / 54);      // XCD k owns bh 4k..4k+3
  const int qt = slot % 54;                  // q-tile 0..53
  const int b = bh >> 3, h = bh & 7;
  const int t = threadIdx.x, w = t >> 6, l = t & 63;
  const int lr = l & 31, hi = l >> 5;

  __shared__ float Obuf[4][32][68];
  __shared__ float Lbuf[4][32];

  const unsigned short* Qb = Qf + ((size_t)bh * 54 + qt) * 2048 + l * 8;
  bf16x8 bq[4];
#pragma unroll
  for (int kf = 0; kf < 4; ++kf) bq[kf] = *(const bf16x8*)(Qb + kf * 512);

  f32x16 oacc[2];
  oacc[0] = zero16(); oacc[1] = zero16();
  float ls = 0.f;

  const unsigned short* Kb = Kf + (size_t)bh * 54 * 2048 + l * 8;
  const unsigned short* Vb = Vf + (size_t)bh * 54 * 2048 + l * 8;

#pragma unroll 1
  for (int ck = w; ck < 54; ck += 4) {
    const unsigned short* kc = Kb + ck * 2048;
    const unsigned short* vc = Vb + ck * 2048;
    bf16x8 ak[4];
#pragma unroll
    for (int i = 0; i < 4; ++i) ak[i] = *(const bf16x8*)(kc + i * 512);

    f32x16 sA = zero16();
#pragma unroll
    for (int kf = 0; kf < 4; ++kf) sA = MFMA32(ak[kf], bq[kf], sA);

    // V loads issued here: registers can reuse ak's slots (dead after QK);
    // ~200cy latency covered by the softmax below.
    bf16x8 vb[4];
#pragma unroll
    for (int i = 0; i < 4; ++i) vb[i] = *(const bf16x8*)(vc + i * 512);

    // softmax: s already scaled (Q pre-scaled) -> bare v_exp (2^x).
    unsigned int W[8];
    float a0 = 0.f, a1 = 0.f;
#pragma unroll
    for (int u = 0; u < 8; ++u) {
      float e0, e1;
      asm("v_exp_f32 %0, %1" : "=v"(e0) : "v"(sA[2 * u]));
      asm("v_exp_f32 %0, %1" : "=v"(e1) : "v"(sA[2 * u + 1]));
      a0 += e0; a1 += e1;
      asm("v_cvt_pk_bf16_f32 %0, %1, %2" : "=v"(W[u]) : "v"(e0), "v"(e1));
    }
    ls += a0 + a1;

    unsigned int fw[2][4];
#pragma unroll
    for (int kf = 0; kf < 2; ++kf)
#pragma unroll
      for (int wd = 0; wd < 2; ++wd) {
        unsigned int lo  = W[4 * kf + wd];
        unsigned int hw  = W[4 * kf + 2 + wd];
        unsigned int pub = hi ? lo : hw;
        unsigned int rcv = (unsigned int)__shfl_xor((int)pub, 32, 64);
        fw[kf][wd]     = hi ? rcv : lo;
        fw[kf][2 + wd] = hi ? hw : rcv;
      }
    u32x4 w0, w1;
    w0[0] = fw[0][0]; w0[1] = fw[0][1]; w0[2] = fw[0][2]; w0[3] = fw[0][3];
    w1[0] = fw[1][0]; w1[1] = fw[1][1]; w1[2] = fw[1][2]; w1[3] = fw[1][3];
    bf16x8 pa0 = __builtin_bit_cast(bf16x8, w0);
    bf16x8 pa1 = __builtin_bit_cast(bf16x8, w1);

    oacc[0] = MFMA32(pa0, vb[0], oacc[0]);
    oacc[0] = MFMA32(pa1, vb[1], oacc[0]);
    oacc[1] = MFMA32(pa0, vb[2], oacc[1]);
    oacc[1] = MFMA32(pa1, vb[3], oacc[1]);
  }

  // ---- epilogue: combine 4 waves via LDS, normalize, store Of
  float lt = ls + __shfl_xor(ls, 32, 64);
  if (l < 32) Lbuf[w][lr] = lt;
#pragma unroll
  for (int dt = 0; dt < 2; ++dt)
#pragma unroll
    for (int r = 0; r < 16; ++r)
      Obuf[w][(r & 3) + 8 * (r >> 2) + 4 * hi][dt * 32 + lr] = oacc[dt][r];
  __syncthreads();

  const int n = t >> 3, d0 = (t & 7) * 8;
  float ltot = Lbuf[0][n] + Lbuf[1][n] + Lbuf[2][n] + Lbuf[3][n];
  float linv = 1.0f / ltot;
  u16x8 o8;
#pragma unroll
  for (int i = 0; i < 8; ++i) {
    float ov = Obuf[0][n][d0 + i] + Obuf[1][n][d0 + i] +
               Obuf[2][n][d0 + i] + Obuf[3][n][d0 + i];
    o8[i] = f2bf(ov * linv);
  }
  size_t off = (size_t)((((b * 27 + (qt >> 1)) * 16 + h * 2 + (d0 >> 5)) * 4 +
                         (qt & 1) * 2 + (n >> 4))) * 512 +
               ((d0 >> 3) & 3) * 128 + (n & 15) * 8;
  *(u16x8*)(Of + off) = o8;
}

// ---------------------------------------------------------------- out proj
// 64x32 tiles per wave, grid 36 x 12 (432 blocks).
__global__ __launch_bounds__(256) void k_gemm_out(
    const unsigned short* __restrict__ Wf, const unsigned short* __restrict__ Of,
    const float* __restrict__ bo,
    const float* __restrict__ f0, const float* __restrict__ f1,
    const float* __restrict__ f2, float* __restrict__ out) {
  const int z = blockIdx.z, b = z / 3, f = z % 3;
  const int t = threadIdx.x, w = t >> 6, l = t & 63, lg = l >> 4, lr = l & 15;
  const int wid = blockIdx.x * 4 + w;        // 0..143 = 8 mt * 9 ntw * 2 half
  const int mt = wid / 18, rest = wid % 18;
  const int ntw = rest >> 1, half = rest & 1;
  const int o0 = mt * 64;
  const unsigned short* A = Wf + (size_t)(3 * 8 + mt) * 16 * 2048 + l * 8;
  const unsigned short* B = Of + (size_t)(b * 27 + f * 9 + ntw) * 16 * 2048 +
                            half * 1024 + l * 8;

  f32x4 acc[4][2];
#pragma unroll
  for (int fr = 0; fr < 4; ++fr)
#pragma unroll
    for (int fc = 0; fc < 2; ++fc) acc[fr][fc] = (f32x4){0.f, 0.f, 0.f, 0.f};

#pragma unroll 2
  for (int ks = 0; ks < 16; ++ks) {
    bf16x8 af[4], bfv[2];
#pragma unroll
    for (int fr = 0; fr < 4; ++fr)
      af[fr] = *(const bf16x8*)(A + ks * 2048 + fr * 512);
#pragma unroll
    for (int fc = 0; fc < 2; ++fc)
      bfv[fc] = *(const bf16x8*)(B + ks * 2048 + fc * 512);
#pragma unroll
    for (int fr = 0; fr < 4; ++fr)
#pragma unroll
      for (int fc = 0; fc < 2; ++fc)
        acc[fr][fc] = MFMA16(af[fr], bfv[fc], acc[fr][fc]);
  }

  const float* ft = f == 0 ? f0 : f == 1 ? f1 : f2;
#pragma unroll
  for (int fr = 0; fr < 4; ++fr) {
    f32x4 b4 = *(const f32x4*)(bo + o0 + fr * 16 + lg * 4);
#pragma unroll
    for (int fc = 0; fc < 2; ++fc) {
      int ncol = ntw * 64 + half * 32 + fc * 16 + lr;
#pragma unroll
      for (int r = 0; r < 4; ++r) {
        int o = o0 + fr * 16 + lg * 4 + r;
        out[((f * 4 + b) * 512 + o) * 576 + ncol] =
            acc[fr][fc][r] + b4[r] + ft[(b * 512 + o) * 576 + ncol];
      }
    }
  }
}

// ---------------------------------------------------------------- launcher
extern "C" void kernel_launch(void* const* d_in, const int* in_sizes, int n_in,
                              void* d_out, int out_size, void* d_ws, size_t ws_size,
                              hipStream_t stream) {
  const float* f0 = (const float*)d_in[0];
  const float* f1 = (const float*)d_in[1];
  const float* f2 = (const float*)d_in[2];
  const float* Wq = (const float*)d_in[3];
  const float* bq = (const float*)d_in[4];
  const float* Wk = (const float*)d_in[5];
  const float* bk = (const float*)d_in[6];
  const float* Wv = (const float*)d_in[7];
  const float* bv = (const float*)d_in[8];
  const float* Wo = (const float*)d_in[9];
  const float* bo = (const float*)d_in[10];
  float* out = (float*)d_out;

  char* ws = (char*)d_ws;
  unsigned short* Wf = (unsigned short*)(ws);
  unsigned short* Xf = (unsigned short*)(ws + 2097152);
  unsigned short* Qf = (unsigned short*)(ws + 9175040);
  unsigned short* Kf = (unsigned short*)(ws + 16252928);
  unsigned short* Vf = (unsigned short*)(ws + 23330816);
  unsigned short* Of = Xf;  // Xf dead after k_gemm_qkv; reused for attention out

  k_prep<<<dim3(1888), 256, 0, stream>>>(Wq, Wk, Wv, Wo, f0, f1, f2, Wf, Xf);
  k_gemm_qkv<<<dim3(1296), 256, 0, stream>>>(Wf, Xf, bq, bk, bv, Qf, Kf, Vf);
  k_attn<<<dim3(1728), 256, 0, stream>>>(Qf, Kf, Vf, Of);
  k_gemm_out<<<dim3(36, 1, 12), 256, 0, stream>>>(Wf, Of, bo, f0, f1, f2, out);
}